// Round 1
// baseline (1699.114 us; speedup 1.0000x reference)
//
#include <hip/hip_runtime.h>
#include <math.h>

// ---------------- problem constants ----------------
#define NENT     100000
#define NREL     474
#define DIM      200
#define NBASES   100
#define NEDGES   500000
#define NTRIPLES 200000

#define CHUNK    25000     // nodes per S-buffer chunk
#define NCHUNKS  4

// workspace byte offsets (1024-aligned)
#define OFF_R1    0UL          // 474*200*4 = 379200
#define OFF_R2    379904UL
#define OFF_R3    759808UL
#define OFF_DEG   1139712UL    // 100000*4
#define OFF_CUR   1540096UL    // 100000*4
#define OFF_CSR   1940480UL    // 100001*4
#define OFF_BSUM  2340864UL    // 98*4
#define OFF_BOFF  2341888UL
#define OFF_CSRC  2342912UL    // 500000*4
#define OFF_CRY   4343808UL    // 500000*4
#define OFF_SBUF  6344704UL    // 25000*600*4 = 60MB
#define OFF_X1    66345984UL   // 100000*200*4 = 80MB
#define OFF_X2    146345984UL  // 80MB
// total = 226,345,984 bytes (~216 MiB) of d_ws

// ---------------- tiny GEMM: C[MxN] = A[MxK] @ B[KxN] ----------------
__global__ __launch_bounds__(256) void k_small_gemm(
    const float* __restrict__ A, const float* __restrict__ B,
    float* __restrict__ C, int M, int K, int N)
{
    int tid = blockIdx.x * blockDim.x + threadIdx.x;
    if (tid >= M * N) return;
    int row = tid / N, col = tid - row * N;
    const float* a = A + (long)row * K;
    float acc = 0.f;
    int k = 0;
    for (; k + 4 <= K; k += 4) {
        acc = fmaf(a[k + 0], B[(k + 0) * N + col], acc);
        acc = fmaf(a[k + 1], B[(k + 1) * N + col], acc);
        acc = fmaf(a[k + 2], B[(k + 2) * N + col], acc);
        acc = fmaf(a[k + 3], B[(k + 3) * N + col], acc);
    }
    for (; k < K; ++k) acc = fmaf(a[k], B[k * N + col], acc);
    C[tid] = acc;
}

// ---------------- CSR build ----------------
__global__ __launch_bounds__(256) void k_hist(const int* __restrict__ ei, int* __restrict__ deg)
{
    int e = blockIdx.x * blockDim.x + threadIdx.x;
    if (e >= NEDGES) return;
    atomicAdd(&deg[ei[NEDGES + e]], 1);
}

__global__ __launch_bounds__(256) void k_scanA(
    const int* __restrict__ deg, int* __restrict__ out, int* __restrict__ bsum)
{
    __shared__ int sd[256];
    int t = threadIdx.x, b = blockIdx.x;
    int base = b * 1024 + t * 4;
    int v0 = (base + 0 < NENT) ? deg[base + 0] : 0;
    int v1 = (base + 1 < NENT) ? deg[base + 1] : 0;
    int v2 = (base + 2 < NENT) ? deg[base + 2] : 0;
    int v3 = (base + 3 < NENT) ? deg[base + 3] : 0;
    int s = v0 + v1 + v2 + v3;
    sd[t] = s; __syncthreads();
    for (int off = 1; off < 256; off <<= 1) {
        int x = (t >= off) ? sd[t - off] : 0;
        __syncthreads();
        sd[t] += x;
        __syncthreads();
    }
    int excl = sd[t] - s;
    if (base + 0 < NENT) out[base + 0] = excl;
    if (base + 1 < NENT) out[base + 1] = excl + v0;
    if (base + 2 < NENT) out[base + 2] = excl + v0 + v1;
    if (base + 3 < NENT) out[base + 3] = excl + v0 + v1 + v2;
    if (t == 255) bsum[b] = sd[255];
}

__global__ __launch_bounds__(128) void k_scanB(
    const int* __restrict__ bsum, int* __restrict__ boff, int nb)
{
    __shared__ int sd[128];
    int t = threadIdx.x;
    int s = (t < nb) ? bsum[t] : 0;
    sd[t] = s; __syncthreads();
    for (int off = 1; off < 128; off <<= 1) {
        int x = (t >= off) ? sd[t - off] : 0;
        __syncthreads();
        sd[t] += x;
        __syncthreads();
    }
    if (t < nb) boff[t] = sd[t] - s;
}

__global__ __launch_bounds__(256) void k_scanC(int* __restrict__ csr, const int* __restrict__ boff)
{
    int t = threadIdx.x, b = blockIdx.x;
    int base = b * 1024 + t * 4;
    int add = boff[b];
    #pragma unroll
    for (int i = 0; i < 4; ++i)
        if (base + i < NENT) csr[base + i] += add;
    if (b == 0 && t == 0) csr[NENT] = NEDGES;
}

__global__ __launch_bounds__(256) void k_scatter(
    const int* __restrict__ ei, const int* __restrict__ et, const int* __restrict__ y,
    const int* __restrict__ csr, int* __restrict__ cur,
    int* __restrict__ csrc, int* __restrict__ cry)
{
    int e = blockIdx.x * blockDim.x + threadIdx.x;
    if (e >= NEDGES) return;
    int dst = ei[NEDGES + e];
    int pos = csr[dst] + atomicAdd(&cur[dst], 1);
    csrc[pos] = ei[e];
    cry[pos]  = et[e] | (y[e] << 16);
}

// ---------------- per-node bucketed message accumulation ----------------
// one wave per node; lanes 0..49 each own a float4 (4 dims) of the 200-dim row
__global__ __launch_bounds__(256) void k_accum(
    const float4* __restrict__ x, const int* __restrict__ indir,
    const float4* __restrict__ r, const int* __restrict__ csr,
    const int* __restrict__ csrc, const int* __restrict__ cry,
    float4* __restrict__ S, int nodeBase)
{
    int wv   = (blockIdx.x * blockDim.x + threadIdx.x) >> 6;   // 0..CHUNK-1
    int lane = threadIdx.x & 63;
    if (lane >= 50) return;
    int v = nodeBase + wv;
    int start = csr[v], end = csr[v + 1];
    float4 a0 = {0,0,0,0}, a1 = {0,0,0,0}, a2 = {0,0,0,0};
    for (int e = start; e < end; ++e) {
        int src = csrc[e];
        if (indir) src = indir[src];
        int ry  = cry[e];
        int rel = ry & 0xFFFF;
        int k   = ry >> 16;
        float4 xv = x[src * 50 + lane];
        float4 rv = r[rel * 50 + lane];
        float4 m;
        m.x = xv.x + rv.x; m.y = xv.y + rv.y; m.z = xv.z + rv.z; m.w = xv.w + rv.w;
        if (k == 0)      { a0.x += m.x; a0.y += m.y; a0.z += m.z; a0.w += m.w; }
        else if (k == 1) { a1.x += m.x; a1.y += m.y; a1.z += m.z; a1.w += m.w; }
        else             { a2.x += m.x; a2.y += m.y; a2.z += m.z; a2.w += m.w; }
    }
    long so = (long)wv * 150;    // 600 floats = 150 float4 per node, chunk-local
    S[so +   0 + lane] = a0;
    S[so +  50 + lane] = a1;
    S[so + 100 + lane] = a2;
}

// ---------------- tiled GEMM: X[rowBase+m][n] = tanh( S[m][0..600) @ W[600][200] ) ----
#define MT 64
#define NT 64
#define KC 40
__global__ __launch_bounds__(256) void k_gemm(
    const float* __restrict__ S, const float* __restrict__ W,
    float* __restrict__ X, int nrows, int rowBase)
{
    __shared__ float Sl[KC][68];   // transposed: Sl[kd][m], 16B-aligned rows (68*4=272)
    __shared__ float Wl[KC][68];
    int tid = threadIdx.x;
    int tx = tid & 15, ty = tid >> 4;
    int row0 = blockIdx.x * MT;
    int n0   = blockIdx.y * NT;
    float acc[4][4] = {};
    for (int kc = 0; kc < 600; kc += KC) {
        // stage S tile (64 rows x KC), transposed into LDS
        for (int idx = tid; idx < 64 * (KC / 4); idx += 256) {
            int m  = idx / (KC / 4);
            int j4 = (idx - m * (KC / 4)) * 4;
            float4 v = {0,0,0,0};
            if (row0 + m < nrows)
                v = *(const float4*)&S[(long)(row0 + m) * 600 + kc + j4];
            Sl[j4 + 0][m] = v.x; Sl[j4 + 1][m] = v.y;
            Sl[j4 + 2][m] = v.z; Sl[j4 + 3][m] = v.w;
        }
        // stage W tile (KC rows x 64 cols)
        for (int idx = tid; idx < KC * 16; idx += 256) {
            int kd = idx / 16;
            int j4 = (idx - kd * 16) * 4;
            float4 v = {0,0,0,0};
            int col = n0 + j4;
            if (col + 4 <= DIM)
                v = *(const float4*)&W[(long)(kc + kd) * DIM + col];
            *(float4*)&Wl[kd][j4] = v;
        }
        __syncthreads();
        #pragma unroll 8
        for (int kd = 0; kd < KC; ++kd) {
            float4 s4 = *(const float4*)&Sl[kd][ty * 4];
            float4 w4 = *(const float4*)&Wl[kd][tx * 4];
            float ss[4] = {s4.x, s4.y, s4.z, s4.w};
            float ww[4] = {w4.x, w4.y, w4.z, w4.w};
            #pragma unroll
            for (int i = 0; i < 4; ++i)
                #pragma unroll
                for (int j = 0; j < 4; ++j)
                    acc[i][j] = fmaf(ss[i], ww[j], acc[i][j]);
        }
        __syncthreads();
    }
    int col = n0 + tx * 4;
    if (col + 4 <= DIM) {
        #pragma unroll
        for (int i = 0; i < 4; ++i) {
            int m = ty * 4 + i;
            if (row0 + m < nrows) {
                float4 o;
                o.x = tanhf(acc[i][0]); o.y = tanhf(acc[i][1]);
                o.z = tanhf(acc[i][2]); o.w = tanhf(acc[i][3]);
                *(float4*)&X[(long)(rowBase + row0 + m) * DIM + col] = o;
            }
        }
    }
}

// ---------------- row L2-normalize (in place) ----------------
__global__ __launch_bounds__(256) void k_norm(float4* __restrict__ x)
{
    int wv   = (blockIdx.x * blockDim.x + threadIdx.x) >> 6;   // node id
    int lane = threadIdx.x & 63;
    float4 v = {0,0,0,0};
    if (lane < 50) v = x[(long)wv * 50 + lane];
    float ss = v.x*v.x + v.y*v.y + v.z*v.z + v.w*v.w;
    for (int off = 1; off < 64; off <<= 1) ss += __shfl_xor(ss, off);
    float scale = 1.f / fmaxf(sqrtf(ss), 1e-12f);
    if (lane < 50) {
        v.x *= scale; v.y *= scale; v.z *= scale; v.w *= scale;
        x[(long)wv * 50 + lane] = v;
    }
}

// ---------------- triple scoring ----------------
__global__ __launch_bounds__(256) void k_score(
    const float4* __restrict__ x, const float4* __restrict__ r,
    const int* __restrict__ tri, float* __restrict__ out)
{
    int wv   = (blockIdx.x * blockDim.x + threadIdx.x) >> 6;   // triple id
    int lane = threadIdx.x & 63;
    if (wv >= NTRIPLES) return;
    int h = tri[wv * 3 + 0], rel = tri[wv * 3 + 1], t = tri[wv * 3 + 2];
    float p = 0.f;
    if (lane < 50) {
        float4 hv = x[(long)h * 50 + lane];
        float4 rv = r[(long)rel * 50 + lane];
        float4 tv = x[(long)t * 50 + lane];
        p = fabsf(hv.x + rv.x - tv.x) + fabsf(hv.y + rv.y - tv.y)
          + fabsf(hv.z + rv.z - tv.z) + fabsf(hv.w + rv.w - tv.w);
    }
    for (int off = 1; off < 64; off <<= 1) p += __shfl_xor(p, off);
    if (lane == 0) out[wv] = 1.f / (1.f + expf(-p));
}

// ---------------- launch ----------------
extern "C" void kernel_launch(void* const* d_in, const int* in_sizes, int n_in,
                              void* d_out, int out_size, void* d_ws, size_t ws_size,
                              hipStream_t stream)
{
    const float* ent    = (const float*)d_in[0];   // 100000 x 200
    const float* bases  = (const float*)d_in[1];   // 100 x 200
    const float* coeff  = (const float*)d_in[2];   // 474 x 100
    const float* w1     = (const float*)d_in[3];   // 3 x 200 x 200  (= 600 x 200)
    const float* rw1    = (const float*)d_in[4];   // 200 x 200
    const float* w2     = (const float*)d_in[5];
    const float* rw2    = (const float*)d_in[6];
    const int*   entids = (const int*)d_in[7];     // 100000
    const int*   ei     = (const int*)d_in[8];     // 2 x 500000
    const int*   etype  = (const int*)d_in[9];     // 500000
    const int*   yv     = (const int*)d_in[10];    // 500000
    const int*   tri    = (const int*)d_in[11];    // 200000 x 3
    float* out = (float*)d_out;

    char* ws = (char*)d_ws;
    float* r1   = (float*)(ws + OFF_R1);
    float* r2   = (float*)(ws + OFF_R2);
    float* r3   = (float*)(ws + OFF_R3);
    int* deg    = (int*)(ws + OFF_DEG);
    int* cur    = (int*)(ws + OFF_CUR);
    int* csr    = (int*)(ws + OFF_CSR);
    int* bsum   = (int*)(ws + OFF_BSUM);
    int* boff   = (int*)(ws + OFF_BOFF);
    int* csrc   = (int*)(ws + OFF_CSRC);
    int* cry    = (int*)(ws + OFF_CRY);
    float* Sbuf = (float*)(ws + OFF_SBUF);
    float* x1   = (float*)(ws + OFF_X1);
    float* x2   = (float*)(ws + OFF_X2);

    // zero deg + cursor (covers both regions incl. padding)
    hipMemsetAsync(ws + OFF_DEG, 0, OFF_CSR - OFF_DEG, stream);

    // relation chain: r1 = coeff@bases ; r2 = r1@rw1 ; r3 = r2@rw2
    {
        int tot = NREL * DIM;
        int nb = (tot + 255) / 256;
        k_small_gemm<<<nb, 256, 0, stream>>>(coeff, bases, r1, NREL, NBASES, DIM);
        k_small_gemm<<<nb, 256, 0, stream>>>(r1, rw1, r2, NREL, DIM, DIM);
        k_small_gemm<<<nb, 256, 0, stream>>>(r2, rw2, r3, NREL, DIM, DIM);
    }

    // CSR by destination (shared by both layers)
    k_hist<<<(NEDGES + 255) / 256, 256, 0, stream>>>(ei, deg);
    int nScanBlocks = (NENT + 1023) / 1024;   // 98
    k_scanA<<<nScanBlocks, 256, 0, stream>>>(deg, csr, bsum);
    k_scanB<<<1, 128, 0, stream>>>(bsum, boff, nScanBlocks);
    k_scanC<<<nScanBlocks, 256, 0, stream>>>(csr, boff);
    k_scatter<<<(NEDGES + 255) / 256, 256, 0, stream>>>(ei, etype, yv, csr, cur, csrc, cry);

    dim3 ggrid((CHUNK + MT - 1) / MT, (DIM + NT - 1) / NT);   // (391, 4)

    // layer 1: x1 = tanh(segsum_bucketed(ent[entids[src]] + r1[et]) @ w1)
    for (int c = 0; c < NCHUNKS; ++c) {
        int base = c * CHUNK;
        k_accum<<<CHUNK / 4, 256, 0, stream>>>(
            (const float4*)ent, entids, (const float4*)r1, csr, csrc, cry,
            (float4*)Sbuf, base);
        k_gemm<<<ggrid, 256, 0, stream>>>(Sbuf, w1, x1, CHUNK, base);
    }
    // layer 2
    for (int c = 0; c < NCHUNKS; ++c) {
        int base = c * CHUNK;
        k_accum<<<CHUNK / 4, 256, 0, stream>>>(
            (const float4*)x1, (const int*)nullptr, (const float4*)r2, csr, csrc, cry,
            (float4*)Sbuf, base);
        k_gemm<<<ggrid, 256, 0, stream>>>(Sbuf, w2, x2, CHUNK, base);
    }

    // normalize rows of x2, then score triples
    k_norm<<<NENT / 4, 256, 0, stream>>>((float4*)x2);
    k_score<<<(NTRIPLES + 3) / 4, 256, 0, stream>>>(
        (const float4*)x2, (const float4*)r3, tri, out);
}

// Round 5
// 846.134 us; speedup vs baseline: 2.0081x; 2.0081x over previous
//
#include <hip/hip_runtime.h>
#include <math.h>

// R5 = R2 resubmitted verbatim (R2-R4 benches all failed: GPU acquisition timeout; never measured).
// R2: bf16-MFMA GEMM (16x16x32), bf16 S-buffer + bf16 gather tables.
// R1 evidence: k_gemm 8x153us, MfmaUtil=0, 7.5M LDS bank conflicts, S re-fetched 2.2x.

// ---------------- problem constants ----------------
#define NENT     100000
#define NREL     474
#define DIM      200
#define NBASES   100
#define NEDGES   500000
#define NTRIPLES 200000

#define CHUNK    50000     // nodes per S-buffer chunk
#define NCHUNKS  2
#define SD       608       // padded S row stride (bf16 elems): 600 data + 8 zero
#define KD       608       // Wt row stride (bf16 elems)
#define NTILES   13        // ceil(208/16) column tiles of 16

// workspace byte offsets (1024-aligned)
#define OFF_R1    0UL           // 474*200*4 = 379200
#define OFF_R2    379904UL
#define OFF_R3    759808UL
#define OFF_DEG   1139712UL     // 100000*4
#define OFF_CUR   1540096UL
#define OFF_CSR   1940480UL     // 100001*4
#define OFF_BSUM  2340864UL
#define OFF_BOFF  2341888UL
#define OFF_CSRC  2342912UL     // 500000*4
#define OFF_CRY   4343808UL     // 500000*4
#define OFF_WT1   6344704UL     // 208*608*2 = 252928
#define OFF_WT2   6598656UL
#define OFF_ENTB  6852608UL     // 100000*200*2 = 40,000,000
#define OFF_X1B   46853120UL    // 40,000,000 (bf16 layer-1 output)
#define OFF_SBUF  86853632UL    // 50000*608*2 = 60,800,000
#define OFF_X2    147654144UL   // 100000*200*4 = 80,000,000
// total = 227,654,144 bytes (~217 MiB)

typedef __attribute__((ext_vector_type(8))) short bf16x8;
typedef __attribute__((ext_vector_type(4))) float f32x4;

__device__ inline unsigned short f2bf(float f) {          // RNE
    unsigned u = __float_as_uint(f);
    return (unsigned short)((u + 0x7FFFu + ((u >> 16) & 1u)) >> 16);
}
__device__ inline float bf2f(unsigned short s) {
    return __uint_as_float(((unsigned)s) << 16);
}

// ---------------- tiny GEMM: C[MxN] = A[MxK] @ B[KxN] (relation chain, fp32) ----
__global__ __launch_bounds__(256) void k_small_gemm(
    const float* __restrict__ A, const float* __restrict__ B,
    float* __restrict__ C, int M, int K, int N)
{
    int tid = blockIdx.x * blockDim.x + threadIdx.x;
    if (tid >= M * N) return;
    int row = tid / N, col = tid - row * N;
    const float* a = A + (long)row * K;
    float acc = 0.f;
    int k = 0;
    for (; k + 4 <= K; k += 4) {
        acc = fmaf(a[k + 0], B[(k + 0) * N + col], acc);
        acc = fmaf(a[k + 1], B[(k + 1) * N + col], acc);
        acc = fmaf(a[k + 2], B[(k + 2) * N + col], acc);
        acc = fmaf(a[k + 3], B[(k + 3) * N + col], acc);
    }
    for (; k < K; ++k) acc = fmaf(a[k], B[k * N + col], acc);
    C[tid] = acc;
}

// ---------------- W[600][200] fp32 -> Wt[208][608] bf16 (transposed, zero-padded) ----
__global__ __launch_bounds__(256) void k_wt(const float* __restrict__ W,
                                            unsigned short* __restrict__ Wt)
{
    int i = blockIdx.x * 256 + threadIdx.x;
    if (i >= 208 * 608) return;
    int c = i / 608, k = i - c * 608;
    float v = (c < 200 && k < 600) ? W[k * 200 + c] : 0.f;
    Wt[i] = f2bf(v);
}

// ---------------- ent[entids] fp32 -> bf16 table ----------------
__global__ __launch_bounds__(256) void k_entb(const float4* __restrict__ ent,
                                              const int* __restrict__ ids,
                                              ushort4* __restrict__ out)
{
    int i = blockIdx.x * 256 + threadIdx.x;     // over NENT*50
    if (i >= NENT * 50) return;
    int node = i / 50, j = i - node * 50;
    float4 v = ent[(long)ids[node] * 50 + j];
    ushort4 o;
    o.x = f2bf(v.x); o.y = f2bf(v.y); o.z = f2bf(v.z); o.w = f2bf(v.w);
    out[i] = o;
}

// ---------------- CSR build ----------------
__global__ __launch_bounds__(256) void k_hist(const int* __restrict__ ei, int* __restrict__ deg)
{
    int e = blockIdx.x * blockDim.x + threadIdx.x;
    if (e >= NEDGES) return;
    atomicAdd(&deg[ei[NEDGES + e]], 1);
}

__global__ __launch_bounds__(256) void k_scanA(
    const int* __restrict__ deg, int* __restrict__ out, int* __restrict__ bsum)
{
    __shared__ int sd[256];
    int t = threadIdx.x, b = blockIdx.x;
    int base = b * 1024 + t * 4;
    int v0 = (base + 0 < NENT) ? deg[base + 0] : 0;
    int v1 = (base + 1 < NENT) ? deg[base + 1] : 0;
    int v2 = (base + 2 < NENT) ? deg[base + 2] : 0;
    int v3 = (base + 3 < NENT) ? deg[base + 3] : 0;
    int s = v0 + v1 + v2 + v3;
    sd[t] = s; __syncthreads();
    for (int off = 1; off < 256; off <<= 1) {
        int x = (t >= off) ? sd[t - off] : 0;
        __syncthreads();
        sd[t] += x;
        __syncthreads();
    }
    int excl = sd[t] - s;
    if (base + 0 < NENT) out[base + 0] = excl;
    if (base + 1 < NENT) out[base + 1] = excl + v0;
    if (base + 2 < NENT) out[base + 2] = excl + v0 + v1;
    if (base + 3 < NENT) out[base + 3] = excl + v0 + v1 + v2;
    if (t == 255) bsum[b] = sd[255];
}

__global__ __launch_bounds__(128) void k_scanB(
    const int* __restrict__ bsum, int* __restrict__ boff, int nb)
{
    __shared__ int sd[128];
    int t = threadIdx.x;
    int s = (t < nb) ? bsum[t] : 0;
    sd[t] = s; __syncthreads();
    for (int off = 1; off < 128; off <<= 1) {
        int x = (t >= off) ? sd[t - off] : 0;
        __syncthreads();
        sd[t] += x;
        __syncthreads();
    }
    if (t < nb) boff[t] = sd[t] - s;
}

__global__ __launch_bounds__(256) void k_scanC(int* __restrict__ csr, const int* __restrict__ boff)
{
    int t = threadIdx.x, b = blockIdx.x;
    int base = b * 1024 + t * 4;
    int add = boff[b];
    #pragma unroll
    for (int i = 0; i < 4; ++i)
        if (base + i < NENT) csr[base + i] += add;
    if (b == 0 && t == 0) csr[NENT] = NEDGES;
}

__global__ __launch_bounds__(256) void k_scatter(
    const int* __restrict__ ei, const int* __restrict__ et, const int* __restrict__ y,
    const int* __restrict__ csr, int* __restrict__ cur,
    int* __restrict__ csrc, int* __restrict__ cry)
{
    int e = blockIdx.x * blockDim.x + threadIdx.x;
    if (e >= NEDGES) return;
    int dst = ei[NEDGES + e];
    int pos = csr[dst] + atomicAdd(&cur[dst], 1);
    csrc[pos] = ei[e];
    cry[pos]  = et[e] | (y[e] << 16);
}

// ---------------- per-node bucketed message accumulation (bf16 gather, bf16 S out) ----
// one wave per node; lanes 0..49 each own 4 dims of the 200-dim row
__global__ __launch_bounds__(256) void k_accum(
    const unsigned short* __restrict__ xb,   // [NENT][200] bf16
    const float4* __restrict__ r,            // [NREL][200] fp32
    const int* __restrict__ csr, const int* __restrict__ csrc, const int* __restrict__ cry,
    unsigned short* __restrict__ S, int nodeBase)
{
    int wv   = (blockIdx.x * blockDim.x + threadIdx.x) >> 6;   // 0..CHUNK-1
    int lane = threadIdx.x & 63;
    unsigned short* srow = S + (long)wv * SD;
    if (lane >= 50) {
        if (lane == 50) {                    // zero the K-pad (cols 600..607)
            uint4 z; z.x = z.y = z.z = z.w = 0u;
            *(uint4*)(srow + 600) = z;
        }
        return;
    }
    int v = nodeBase + wv;
    int start = csr[v], end = csr[v + 1];
    float4 a0 = {0,0,0,0}, a1 = {0,0,0,0}, a2 = {0,0,0,0};
    for (int e = start; e < end; ++e) {
        int src = csrc[e];
        int ry  = cry[e];
        int rel = ry & 0xFFFF;
        int k   = ry >> 16;
        ushort4 xv = *(const ushort4*)(xb + (long)src * 200 + lane * 4);
        float4  rv = r[(long)rel * 50 + lane];
        float mx = bf2f(xv.x) + rv.x, my = bf2f(xv.y) + rv.y;
        float mz = bf2f(xv.z) + rv.z, mw = bf2f(xv.w) + rv.w;
        if (k == 0)      { a0.x += mx; a0.y += my; a0.z += mz; a0.w += mw; }
        else if (k == 1) { a1.x += mx; a1.y += my; a1.z += mz; a1.w += mw; }
        else             { a2.x += mx; a2.y += my; a2.z += mz; a2.w += mw; }
    }
    ushort4 o;
    o.x = f2bf(a0.x); o.y = f2bf(a0.y); o.z = f2bf(a0.z); o.w = f2bf(a0.w);
    *(ushort4*)(srow +   0 + lane * 4) = o;
    o.x = f2bf(a1.x); o.y = f2bf(a1.y); o.z = f2bf(a1.z); o.w = f2bf(a1.w);
    *(ushort4*)(srow + 200 + lane * 4) = o;
    o.x = f2bf(a2.x); o.y = f2bf(a2.y); o.z = f2bf(a2.z); o.w = f2bf(a2.w);
    *(ushort4*)(srow + 400 + lane * 4) = o;
}

// ---------------- MFMA GEMM: X = tanh( S[M x 608]bf16 @ Wt^T[608 x 208]bf16 ) ------
// Block = 4 waves; each wave owns a 32-row strip x all 13 col-tiles.
// A frag: lane l holds S[row0+(l&15)][kt*32 + (l>>4)*8 + 0..7]   (16B load)
// B frag: lane l holds Wt[nt*16+(l&15)][kt*32 + (l>>4)*8 + 0..7] (16B load, L2-hot)
// C frag: lane l holds C[(l>>4)*4 + i][l&15]
template<int OUTBF>
__global__ __launch_bounds__(256) void k_gemm_mfma(
    const unsigned short* __restrict__ S, const unsigned short* __restrict__ Wt,
    void* __restrict__ Xout, int nrows, int rowBase)
{
    int wid  = threadIdx.x >> 6;
    int lane = threadIdx.x & 63;
    int l15  = lane & 15;
    int l4   = lane >> 4;
    int row0 = (blockIdx.x * 4 + wid) * 32;
    int ra = row0 + l15;       if (ra >= nrows) ra = nrows - 1;
    int rb = row0 + 16 + l15;  if (rb >= nrows) rb = nrows - 1;
    const unsigned short* pa = S  + (long)ra * SD + l4 * 8;
    const unsigned short* pb = S  + (long)rb * SD + l4 * 8;
    const unsigned short* pw = Wt + (long)l15 * KD + l4 * 8;

    f32x4 acc0[NTILES] = {};
    f32x4 acc1[NTILES] = {};
    for (int kt = 0; kt < 19; ++kt) {
        bf16x8 a0 = *(const bf16x8*)(pa + kt * 32);
        bf16x8 a1 = *(const bf16x8*)(pb + kt * 32);
        #pragma unroll
        for (int nt = 0; nt < NTILES; ++nt) {
            bf16x8 b = *(const bf16x8*)(pw + nt * 16 * KD + kt * 32);
            acc0[nt] = __builtin_amdgcn_mfma_f32_16x16x32_bf16(a0, b, acc0[nt], 0, 0, 0);
            acc1[nt] = __builtin_amdgcn_mfma_f32_16x16x32_bf16(a1, b, acc1[nt], 0, 0, 0);
        }
    }
    #pragma unroll
    for (int nt = 0; nt < NTILES; ++nt) {
        int col = nt * 16 + l15;
        bool cok = (col < DIM);
        #pragma unroll
        for (int i = 0; i < 4; ++i) {
            int r0 = row0 + l4 * 4 + i;
            if (cok && r0 < nrows) {
                float v = tanhf(acc0[nt][i]);
                if (OUTBF) ((unsigned short*)Xout)[(long)(rowBase + r0) * DIM + col] = f2bf(v);
                else       ((float*)Xout)[(long)(rowBase + r0) * DIM + col] = v;
            }
            int r1 = r0 + 16;
            if (cok && r1 < nrows) {
                float v = tanhf(acc1[nt][i]);
                if (OUTBF) ((unsigned short*)Xout)[(long)(rowBase + r1) * DIM + col] = f2bf(v);
                else       ((float*)Xout)[(long)(rowBase + r1) * DIM + col] = v;
            }
        }
    }
}

// ---------------- row L2-normalize (in place, fp32) ----------------
__global__ __launch_bounds__(256) void k_norm(float4* __restrict__ x)
{
    int wv   = (blockIdx.x * blockDim.x + threadIdx.x) >> 6;
    int lane = threadIdx.x & 63;
    float4 v = {0,0,0,0};
    if (lane < 50) v = x[(long)wv * 50 + lane];
    float ss = v.x*v.x + v.y*v.y + v.z*v.z + v.w*v.w;
    for (int off = 1; off < 64; off <<= 1) ss += __shfl_xor(ss, off);
    float scale = 1.f / fmaxf(sqrtf(ss), 1e-12f);
    if (lane < 50) {
        v.x *= scale; v.y *= scale; v.z *= scale; v.w *= scale;
        x[(long)wv * 50 + lane] = v;
    }
}

// ---------------- triple scoring ----------------
__global__ __launch_bounds__(256) void k_score(
    const float4* __restrict__ x, const float4* __restrict__ r,
    const int* __restrict__ tri, float* __restrict__ out)
{
    int wv   = (blockIdx.x * blockDim.x + threadIdx.x) >> 6;
    int lane = threadIdx.x & 63;
    if (wv >= NTRIPLES) return;
    int h = tri[wv * 3 + 0], rel = tri[wv * 3 + 1], t = tri[wv * 3 + 2];
    float p = 0.f;
    if (lane < 50) {
        float4 hv = x[(long)h * 50 + lane];
        float4 rv = r[(long)rel * 50 + lane];
        float4 tv = x[(long)t * 50 + lane];
        p = fabsf(hv.x + rv.x - tv.x) + fabsf(hv.y + rv.y - tv.y)
          + fabsf(hv.z + rv.z - tv.z) + fabsf(hv.w + rv.w - tv.w);
    }
    for (int off = 1; off < 64; off <<= 1) p += __shfl_xor(p, off);
    if (lane == 0) out[wv] = 1.f / (1.f + expf(-p));
}

// ---------------- launch ----------------
extern "C" void kernel_launch(void* const* d_in, const int* in_sizes, int n_in,
                              void* d_out, int out_size, void* d_ws, size_t ws_size,
                              hipStream_t stream)
{
    const float* ent    = (const float*)d_in[0];
    const float* bases  = (const float*)d_in[1];
    const float* coeff  = (const float*)d_in[2];
    const float* w1     = (const float*)d_in[3];
    const float* rw1    = (const float*)d_in[4];
    const float* w2     = (const float*)d_in[5];
    const float* rw2    = (const float*)d_in[6];
    const int*   entids = (const int*)d_in[7];
    const int*   ei     = (const int*)d_in[8];
    const int*   etype  = (const int*)d_in[9];
    const int*   yv     = (const int*)d_in[10];
    const int*   tri    = (const int*)d_in[11];
    float* out = (float*)d_out;

    char* ws = (char*)d_ws;
    float* r1   = (float*)(ws + OFF_R1);
    float* r2   = (float*)(ws + OFF_R2);
    float* r3   = (float*)(ws + OFF_R3);
    int* deg    = (int*)(ws + OFF_DEG);
    int* cur    = (int*)(ws + OFF_CUR);
    int* csr    = (int*)(ws + OFF_CSR);
    int* bsum   = (int*)(ws + OFF_BSUM);
    int* boff   = (int*)(ws + OFF_BOFF);
    int* csrc   = (int*)(ws + OFF_CSRC);
    int* cry    = (int*)(ws + OFF_CRY);
    unsigned short* wt1  = (unsigned short*)(ws + OFF_WT1);
    unsigned short* wt2  = (unsigned short*)(ws + OFF_WT2);
    unsigned short* entb = (unsigned short*)(ws + OFF_ENTB);
    unsigned short* x1b  = (unsigned short*)(ws + OFF_X1B);
    unsigned short* Sbuf = (unsigned short*)(ws + OFF_SBUF);
    float* x2   = (float*)(ws + OFF_X2);

    hipMemsetAsync(ws + OFF_DEG, 0, OFF_CSR - OFF_DEG, stream);

    // relation chain (fp32): r1 = coeff@bases ; r2 = r1@rw1 ; r3 = r2@rw2
    {
        int tot = NREL * DIM;
        int nb = (tot + 255) / 256;
        k_small_gemm<<<nb, 256, 0, stream>>>(coeff, bases, r1, NREL, NBASES, DIM);
        k_small_gemm<<<nb, 256, 0, stream>>>(r1, rw1, r2, NREL, DIM, DIM);
        k_small_gemm<<<nb, 256, 0, stream>>>(r2, rw2, r3, NREL, DIM, DIM);
    }

    // weight transpose->bf16, entity table->bf16
    k_wt<<<(208 * 608 + 255) / 256, 256, 0, stream>>>(w1, wt1);
    k_wt<<<(208 * 608 + 255) / 256, 256, 0, stream>>>(w2, wt2);
    k_entb<<<(NENT * 50 + 255) / 256, 256, 0, stream>>>(
        (const float4*)ent, entids, (ushort4*)entb);

    // CSR by destination (shared by both layers)
    k_hist<<<(NEDGES + 255) / 256, 256, 0, stream>>>(ei, deg);
    int nScanBlocks = (NENT + 1023) / 1024;   // 98
    k_scanA<<<nScanBlocks, 256, 0, stream>>>(deg, csr, bsum);
    k_scanB<<<1, 128, 0, stream>>>(bsum, boff, nScanBlocks);
    k_scanC<<<nScanBlocks, 256, 0, stream>>>(csr, boff);
    k_scatter<<<(NEDGES + 255) / 256, 256, 0, stream>>>(ei, etype, yv, csr, cur, csrc, cry);

    int gblocks = (CHUNK + 127) / 128;     // 391 (4 waves x 32 rows per block)

    // layer 1: x1b = bf16(tanh(bucketed-segsum(entb[src]+r1[et]) @ w1))
    for (int c = 0; c < NCHUNKS; ++c) {
        int base = c * CHUNK;
        k_accum<<<CHUNK * 64 / 256, 256, 0, stream>>>(entb, (const float4*)r1,
                                                      csr, csrc, cry, Sbuf, base);
        k_gemm_mfma<1><<<gblocks, 256, 0, stream>>>(Sbuf, wt1, (void*)x1b, CHUNK, base);
    }
    // layer 2: x2 = tanh(bucketed-segsum(x1b[src]+r2[et]) @ w2)   (fp32 out)
    for (int c = 0; c < NCHUNKS; ++c) {
        int base = c * CHUNK;
        k_accum<<<CHUNK * 64 / 256, 256, 0, stream>>>(x1b, (const float4*)r2,
                                                      csr, csrc, cry, Sbuf, base);
        k_gemm_mfma<0><<<gblocks, 256, 0, stream>>>(Sbuf, wt2, (void*)x2, CHUNK, base);
    }

    k_norm<<<NENT / 4, 256, 0, stream>>>((float4*)x2);
    k_score<<<(NTRIPLES + 3) / 4, 256, 0, stream>>>(
        (const float4*)x2, (const float4*)r3, tri, out);
}

// Round 8
// 799.047 us; speedup vs baseline: 2.1264x; 1.0589x over previous
//
#include <hip/hip_runtime.h>
#include <math.h>

// R8 = R6 resubmitted verbatim (R6: acquisition timeout; R7: container failed twice —
// never measured). R6: GEMM re-tiled for occupancy. R5 evidence: k_gemm_mfma 126us x4,
// Occupancy 17% (grid 391 blocks = 1.5/CU), VGPR 112 (acc tile alone = 104 -> no load
// pipelining), MfmaUtil 3.7%, VALUBusy 8.7%, HBM 7.5% => latency-bound.
// Fix: wave tile 32x208 -> 16x112 (acc 104->28 VGPR), N padded to 224 (14 tiles,
// 7/wave), grid 391 -> 1563 blocks (6.1 blocks/CU, ~24 waves/CU).
// Secondary: relation tables bf16 for accum gather (800->400 B/edge on r-rows).

// ---------------- problem constants ----------------
#define NENT     100000
#define NREL     474
#define DIM      200
#define NBASES   100
#define NEDGES   500000
#define NTRIPLES 200000

#define CHUNK    50000     // nodes per S-buffer chunk
#define NCHUNKS  2
#define SD       608       // padded S row stride (bf16): 600 data + 8 zero
#define KD       608       // Wt row stride (bf16)
#define NPAD     224       // padded N (14 col-tiles of 16)
#define NTILW    7         // col-tiles per wave (4 waves: 2 row x 2 col groups)

// workspace byte offsets (4096-aligned regions)
#define OFF_R1    0UL           // 474*200*4 = 379200
#define OFF_R2    380928UL
#define OFF_R3    761856UL
#define OFF_R1B   1142784UL     // 474*200*2 = 189600 (bf16)
#define OFF_R2B   1335296UL
#define OFF_DEG   1527808UL     // 100000*4
#define OFF_CUR   1929216UL
#define OFF_CSR   2330624UL     // 100001*4
#define OFF_BSUM  2732032UL
#define OFF_BOFF  2736128UL
#define OFF_CSRC  2740224UL     // 500000*4
#define OFF_CRY   4743168UL     // 500000*4
#define OFF_WT1   6746112UL     // 224*608*2 = 272384
#define OFF_WT2   7020544UL
#define OFF_ENTB  7294976UL     // 100000*200*2 = 40,000,000
#define OFF_X1B   47296512UL    // 40,000,000 (bf16 layer-1 output)
#define OFF_SBUF  87298048UL    // 50000*608*2 = 60,800,000
#define OFF_X2    148099072UL   // 100000*200*4 = 80,000,000
// total = 228,099,072 bytes (~217.5 MiB; R5's 227.7 MB passed)

typedef __attribute__((ext_vector_type(8))) short bf16x8;
typedef __attribute__((ext_vector_type(4))) float f32x4;

__device__ inline unsigned short f2bf(float f) {          // RNE
    unsigned u = __float_as_uint(f);
    return (unsigned short)((u + 0x7FFFu + ((u >> 16) & 1u)) >> 16);
}
__device__ inline float bf2f(unsigned short s) {
    return __uint_as_float(((unsigned)s) << 16);
}

// ---------------- tiny GEMM: C[MxN] = A[MxK] @ B[KxN] (relation chain, fp32) ----
__global__ __launch_bounds__(256) void k_small_gemm(
    const float* __restrict__ A, const float* __restrict__ B,
    float* __restrict__ C, int M, int K, int N)
{
    int tid = blockIdx.x * blockDim.x + threadIdx.x;
    if (tid >= M * N) return;
    int row = tid / N, col = tid - row * N;
    const float* a = A + (long)row * K;
    float acc = 0.f;
    int k = 0;
    for (; k + 4 <= K; k += 4) {
        acc = fmaf(a[k + 0], B[(k + 0) * N + col], acc);
        acc = fmaf(a[k + 1], B[(k + 1) * N + col], acc);
        acc = fmaf(a[k + 2], B[(k + 2) * N + col], acc);
        acc = fmaf(a[k + 3], B[(k + 3) * N + col], acc);
    }
    for (; k < K; ++k) acc = fmaf(a[k], B[k * N + col], acc);
    C[tid] = acc;
}

// ---------------- fp32 -> bf16 table (relations) ----------------
__global__ __launch_bounds__(256) void k_rb(const float* __restrict__ in,
                                            unsigned short* __restrict__ out, int n)
{
    int i = blockIdx.x * 256 + threadIdx.x;
    if (i < n) out[i] = f2bf(in[i]);
}

// ---------------- W[600][200] fp32 -> Wt[224][608] bf16 (transposed, padded) ----
__global__ __launch_bounds__(256) void k_wt(const float* __restrict__ W,
                                            unsigned short* __restrict__ Wt)
{
    int i = blockIdx.x * 256 + threadIdx.x;
    if (i >= NPAD * KD) return;
    int c = i / KD, k = i - c * KD;
    float v = (c < 200 && k < 600) ? W[k * 200 + c] : 0.f;
    Wt[i] = f2bf(v);
}

// ---------------- ent[entids] fp32 -> bf16 table ----------------
__global__ __launch_bounds__(256) void k_entb(const float4* __restrict__ ent,
                                              const int* __restrict__ ids,
                                              ushort4* __restrict__ out)
{
    int i = blockIdx.x * 256 + threadIdx.x;     // over NENT*50
    if (i >= NENT * 50) return;
    int node = i / 50, j = i - node * 50;
    float4 v = ent[(long)ids[node] * 50 + j];
    ushort4 o;
    o.x = f2bf(v.x); o.y = f2bf(v.y); o.z = f2bf(v.z); o.w = f2bf(v.w);
    out[i] = o;
}

// ---------------- CSR build ----------------
__global__ __launch_bounds__(256) void k_hist(const int* __restrict__ ei, int* __restrict__ deg)
{
    int e = blockIdx.x * blockDim.x + threadIdx.x;
    if (e >= NEDGES) return;
    atomicAdd(&deg[ei[NEDGES + e]], 1);
}

__global__ __launch_bounds__(256) void k_scanA(
    const int* __restrict__ deg, int* __restrict__ out, int* __restrict__ bsum)
{
    __shared__ int sd[256];
    int t = threadIdx.x, b = blockIdx.x;
    int base = b * 1024 + t * 4;
    int v0 = (base + 0 < NENT) ? deg[base + 0] : 0;
    int v1 = (base + 1 < NENT) ? deg[base + 1] : 0;
    int v2 = (base + 2 < NENT) ? deg[base + 2] : 0;
    int v3 = (base + 3 < NENT) ? deg[base + 3] : 0;
    int s = v0 + v1 + v2 + v3;
    sd[t] = s; __syncthreads();
    for (int off = 1; off < 256; off <<= 1) {
        int x = (t >= off) ? sd[t - off] : 0;
        __syncthreads();
        sd[t] += x;
        __syncthreads();
    }
    int excl = sd[t] - s;
    if (base + 0 < NENT) out[base + 0] = excl;
    if (base + 1 < NENT) out[base + 1] = excl + v0;
    if (base + 2 < NENT) out[base + 2] = excl + v0 + v1;
    if (base + 3 < NENT) out[base + 3] = excl + v0 + v1 + v2;
    if (t == 255) bsum[b] = sd[255];
}

__global__ __launch_bounds__(128) void k_scanB(
    const int* __restrict__ bsum, int* __restrict__ boff, int nb)
{
    __shared__ int sd[128];
    int t = threadIdx.x;
    int s = (t < nb) ? bsum[t] : 0;
    sd[t] = s; __syncthreads();
    for (int off = 1; off < 128; off <<= 1) {
        int x = (t >= off) ? sd[t - off] : 0;
        __syncthreads();
        sd[t] += x;
        __syncthreads();
    }
    if (t < nb) boff[t] = sd[t] - s;
}

__global__ __launch_bounds__(256) void k_scanC(int* __restrict__ csr, const int* __restrict__ boff)
{
    int t = threadIdx.x, b = blockIdx.x;
    int base = b * 1024 + t * 4;
    int add = boff[b];
    #pragma unroll
    for (int i = 0; i < 4; ++i)
        if (base + i < NENT) csr[base + i] += add;
    if (b == 0 && t == 0) csr[NENT] = NEDGES;
}

__global__ __launch_bounds__(256) void k_scatter(
    const int* __restrict__ ei, const int* __restrict__ et, const int* __restrict__ y,
    const int* __restrict__ csr, int* __restrict__ cur,
    int* __restrict__ csrc, int* __restrict__ cry)
{
    int e = blockIdx.x * blockDim.x + threadIdx.x;
    if (e >= NEDGES) return;
    int dst = ei[NEDGES + e];
    int pos = csr[dst] + atomicAdd(&cur[dst], 1);
    csrc[pos] = ei[e];
    cry[pos]  = et[e] | (y[e] << 16);
}

// ---------------- per-node bucketed message accumulation (all-bf16 gather) ----------
// one wave per node; lanes 0..49 each own 4 dims of the 200-dim row
__global__ __launch_bounds__(256) void k_accum(
    const unsigned short* __restrict__ xb,   // [NENT][200] bf16
    const unsigned short* __restrict__ rb,   // [NREL][200] bf16
    const int* __restrict__ csr, const int* __restrict__ csrc, const int* __restrict__ cry,
    unsigned short* __restrict__ S, int nodeBase)
{
    int wv   = (blockIdx.x * blockDim.x + threadIdx.x) >> 6;   // 0..CHUNK-1
    int lane = threadIdx.x & 63;
    unsigned short* srow = S + (long)wv * SD;
    if (lane >= 50) {
        if (lane == 50) {                    // zero the K-pad (cols 600..607)
            uint4 z; z.x = z.y = z.z = z.w = 0u;
            *(uint4*)(srow + 600) = z;
        }
        return;
    }
    int v = nodeBase + wv;
    int start = csr[v], end = csr[v + 1];
    float4 a0 = {0,0,0,0}, a1 = {0,0,0,0}, a2 = {0,0,0,0};
    for (int e = start; e < end; ++e) {
        int src = csrc[e];
        int ry  = cry[e];
        int rel = ry & 0xFFFF;
        int k   = ry >> 16;
        ushort4 xv = *(const ushort4*)(xb + (long)src * 200 + lane * 4);
        ushort4 rv = *(const ushort4*)(rb + (long)rel * 200 + lane * 4);
        float mx = bf2f(xv.x) + bf2f(rv.x), my = bf2f(xv.y) + bf2f(rv.y);
        float mz = bf2f(xv.z) + bf2f(rv.z), mw = bf2f(xv.w) + bf2f(rv.w);
        if (k == 0)      { a0.x += mx; a0.y += my; a0.z += mz; a0.w += mw; }
        else if (k == 1) { a1.x += mx; a1.y += my; a1.z += mz; a1.w += mw; }
        else             { a2.x += mx; a2.y += my; a2.z += mz; a2.w += mw; }
    }
    ushort4 o;
    o.x = f2bf(a0.x); o.y = f2bf(a0.y); o.z = f2bf(a0.z); o.w = f2bf(a0.w);
    *(ushort4*)(srow +   0 + lane * 4) = o;
    o.x = f2bf(a1.x); o.y = f2bf(a1.y); o.z = f2bf(a1.z); o.w = f2bf(a1.w);
    *(ushort4*)(srow + 200 + lane * 4) = o;
    o.x = f2bf(a2.x); o.y = f2bf(a2.y); o.z = f2bf(a2.z); o.w = f2bf(a2.w);
    *(ushort4*)(srow + 400 + lane * 4) = o;
}

// ---------------- MFMA GEMM: X = tanh( S[M x 608]bf16 @ Wt^T[608 x 224]bf16 ) ------
// Block = 4 waves = 32 rows x 224 cols; wave = 16 rows x 7 col-tiles (acc 28 VGPR).
// Grid = ceil(nrows/32) = 1563 blocks -> ~6 blocks/CU (fixes R5's 17% occupancy).
// A frag: lane l holds S[row0+(l&15)][kt*32 + (l>>4)*8 + 0..7]   (16B load)
// B frag: lane l holds Wt[ntg*16+(l&15)][kt*32 + (l>>4)*8 + 0..7] (16B load, L2-hot)
// C frag: lane l holds C[row0 + (l>>4)*4 + i][ntg*16 + (l&15)]
template<int OUTBF>
__global__ __launch_bounds__(256) void k_gemm_mfma(
    const unsigned short* __restrict__ S, const unsigned short* __restrict__ Wt,
    void* __restrict__ Xout, int nrows, int rowBase)
{
    int wid  = threadIdx.x >> 6;          // 0..3
    int lane = threadIdx.x & 63;
    int l15  = lane & 15;
    int l4   = lane >> 4;
    int row0 = blockIdx.x * 32 + (wid & 1) * 16;
    int nt0  = (wid >> 1) * NTILW;        // 0 or 7
    int ra = row0 + l15; if (ra >= nrows) ra = nrows - 1;   // clamp reads only
    const unsigned short* pa = S  + (long)ra * SD + l4 * 8;
    const unsigned short* pw = Wt + (long)(nt0 * 16 + l15) * KD + l4 * 8;

    f32x4 acc[NTILW] = {};
    for (int kt = 0; kt < 19; ++kt) {
        bf16x8 a = *(const bf16x8*)(pa + kt * 32);
        #pragma unroll
        for (int nt = 0; nt < NTILW; ++nt) {
            bf16x8 b = *(const bf16x8*)(pw + nt * 16 * KD + kt * 32);
            acc[nt] = __builtin_amdgcn_mfma_f32_16x16x32_bf16(a, b, acc[nt], 0, 0, 0);
        }
    }
    #pragma unroll
    for (int nt = 0; nt < NTILW; ++nt) {
        int col = (nt0 + nt) * 16 + l15;
        bool cok = (col < DIM);
        #pragma unroll
        for (int i = 0; i < 4; ++i) {
            int r = row0 + l4 * 4 + i;
            if (cok && r < nrows) {
                float v = tanhf(acc[nt][i]);
                if (OUTBF) ((unsigned short*)Xout)[(long)(rowBase + r) * DIM + col] = f2bf(v);
                else       ((float*)Xout)[(long)(rowBase + r) * DIM + col] = v;
            }
        }
    }
}

// ---------------- row L2-normalize (in place, fp32) ----------------
__global__ __launch_bounds__(256) void k_norm(float4* __restrict__ x)
{
    int wv   = (blockIdx.x * blockDim.x + threadIdx.x) >> 6;
    int lane = threadIdx.x & 63;
    float4 v = {0,0,0,0};
    if (lane < 50) v = x[(long)wv * 50 + lane];
    float ss = v.x*v.x + v.y*v.y + v.z*v.z + v.w*v.w;
    for (int off = 1; off < 64; off <<= 1) ss += __shfl_xor(ss, off);
    float scale = 1.f / fmaxf(sqrtf(ss), 1e-12f);
    if (lane < 50) {
        v.x *= scale; v.y *= scale; v.z *= scale; v.w *= scale;
        x[(long)wv * 50 + lane] = v;
    }
}

// ---------------- triple scoring ----------------
__global__ __launch_bounds__(256) void k_score(
    const float4* __restrict__ x, const float4* __restrict__ r,
    const int* __restrict__ tri, float* __restrict__ out)
{
    int wv   = (blockIdx.x * blockDim.x + threadIdx.x) >> 6;
    int lane = threadIdx.x & 63;
    if (wv >= NTRIPLES) return;
    int h = tri[wv * 3 + 0], rel = tri[wv * 3 + 1], t = tri[wv * 3 + 2];
    float p = 0.f;
    if (lane < 50) {
        float4 hv = x[(long)h * 50 + lane];
        float4 rv = r[(long)rel * 50 + lane];
        float4 tv = x[(long)t * 50 + lane];
        p = fabsf(hv.x + rv.x - tv.x) + fabsf(hv.y + rv.y - tv.y)
          + fabsf(hv.z + rv.z - tv.z) + fabsf(hv.w + rv.w - tv.w);
    }
    for (int off = 1; off < 64; off <<= 1) p += __shfl_xor(p, off);
    if (lane == 0) out[wv] = 1.f / (1.f + expf(-p));
}

// ---------------- launch ----------------
extern "C" void kernel_launch(void* const* d_in, const int* in_sizes, int n_in,
                              void* d_out, int out_size, void* d_ws, size_t ws_size,
                              hipStream_t stream)
{
    const float* ent    = (const float*)d_in[0];
    const float* bases  = (const float*)d_in[1];
    const float* coeff  = (const float*)d_in[2];
    const float* w1     = (const float*)d_in[3];
    const float* rw1    = (const float*)d_in[4];
    const float* w2     = (const float*)d_in[5];
    const float* rw2    = (const float*)d_in[6];
    const int*   entids = (const int*)d_in[7];
    const int*   ei     = (const int*)d_in[8];
    const int*   etype  = (const int*)d_in[9];
    const int*   yv     = (const int*)d_in[10];
    const int*   tri    = (const int*)d_in[11];
    float* out = (float*)d_out;

    char* ws = (char*)d_ws;
    float* r1   = (float*)(ws + OFF_R1);
    float* r2   = (float*)(ws + OFF_R2);
    float* r3   = (float*)(ws + OFF_R3);
    unsigned short* r1b = (unsigned short*)(ws + OFF_R1B);
    unsigned short* r2b = (unsigned short*)(ws + OFF_R2B);
    int* deg    = (int*)(ws + OFF_DEG);
    int* cur    = (int*)(ws + OFF_CUR);
    int* csr    = (int*)(ws + OFF_CSR);
    int* bsum   = (int*)(ws + OFF_BSUM);
    int* boff   = (int*)(ws + OFF_BOFF);
    int* csrc   = (int*)(ws + OFF_CSRC);
    int* cry    = (int*)(ws + OFF_CRY);
    unsigned short* wt1  = (unsigned short*)(ws + OFF_WT1);
    unsigned short* wt2  = (unsigned short*)(ws + OFF_WT2);
    unsigned short* entb = (unsigned short*)(ws + OFF_ENTB);
    unsigned short* x1b  = (unsigned short*)(ws + OFF_X1B);
    unsigned short* Sbuf = (unsigned short*)(ws + OFF_SBUF);
    float* x2   = (float*)(ws + OFF_X2);

    hipMemsetAsync(ws + OFF_DEG, 0, OFF_CSR - OFF_DEG, stream);

    // relation chain (fp32): r1 = coeff@bases ; r2 = r1@rw1 ; r3 = r2@rw2
    {
        int tot = NREL * DIM;
        int nb = (tot + 255) / 256;
        k_small_gemm<<<nb, 256, 0, stream>>>(coeff, bases, r1, NREL, NBASES, DIM);
        k_small_gemm<<<nb, 256, 0, stream>>>(r1, rw1, r2, NREL, DIM, DIM);
        k_small_gemm<<<nb, 256, 0, stream>>>(r2, rw2, r3, NREL, DIM, DIM);
        k_rb<<<nb, 256, 0, stream>>>(r1, r1b, tot);
        k_rb<<<nb, 256, 0, stream>>>(r2, r2b, tot);
    }

    // weight transpose->bf16 (padded to 224 rows), entity table->bf16
    k_wt<<<(NPAD * KD + 255) / 256, 256, 0, stream>>>(w1, wt1);
    k_wt<<<(NPAD * KD + 255) / 256, 256, 0, stream>>>(w2, wt2);
    k_entb<<<(NENT * 50 + 255) / 256, 256, 0, stream>>>(
        (const float4*)ent, entids, (ushort4*)entb);

    // CSR by destination (shared by both layers)
    k_hist<<<(NEDGES + 255) / 256, 256, 0, stream>>>(ei, deg);
    int nScanBlocks = (NENT + 1023) / 1024;   // 98
    k_scanA<<<nScanBlocks, 256, 0, stream>>>(deg, csr, bsum);
    k_scanB<<<1, 128, 0, stream>>>(bsum, boff, nScanBlocks);
    k_scanC<<<nScanBlocks, 256, 0, stream>>>(csr, boff);
    k_scatter<<<(NEDGES + 255) / 256, 256, 0, stream>>>(ei, etype, yv, csr, cur, csrc, cry);

    int gblocks = (CHUNK + 31) / 32;     // 1563 blocks (4 waves: 2 row x 2 col groups)

    // layer 1: x1b = bf16(tanh(bucketed-segsum(entb[src]+r1[et]) @ w1))
    for (int c = 0; c < NCHUNKS; ++c) {
        int base = c * CHUNK;
        k_accum<<<CHUNK * 64 / 256, 256, 0, stream>>>(entb, r1b,
                                                      csr, csrc, cry, Sbuf, base);
        k_gemm_mfma<1><<<gblocks, 256, 0, stream>>>(Sbuf, wt1, (void*)x1b, CHUNK, base);
    }
    // layer 2: x2 = tanh(bucketed-segsum(x1b[src]+r2[et]) @ w2)   (fp32 out)
    for (int c = 0; c < NCHUNKS; ++c) {
        int base = c * CHUNK;
        k_accum<<<CHUNK * 64 / 256, 256, 0, stream>>>(x1b, r2b,
                                                      csr, csrc, cry, Sbuf, base);
        k_gemm_mfma<0><<<gblocks, 256, 0, stream>>>(Sbuf, wt2, (void*)x2, CHUNK, base);
    }

    k_norm<<<NENT / 4, 256, 0, stream>>>((float4*)x2);
    k_score<<<(NTRIPLES + 3) / 4, 256, 0, stream>>>(
        (const float4*)x2, (const float4*)r3, tri, out);
}

// Round 10
// 790.869 us; speedup vs baseline: 2.1484x; 1.0103x over previous
//
#include <hip/hip_runtime.h>
#include <math.h>

// R10 = R9 resubmitted verbatim (R9 bench failed: GPU acquisition timeout; never measured).
// R9: LDS-staged A via __builtin_amdgcn_global_load_lds (width 16).
// R8 evidence: k_gemm_mfma 77us x4, Occupancy 31%, VGPR 52, MfmaUtil 6.5%,
// VALUBusy 13%, HBM 12%, 0 conflicts => still latency-bound: 7 MFMAs hang off one
// serial global A-load (S is 60.8MB, L3/HBM ~600cy); compiler won't deep-pipeline.
// Fix: stage 32x616 S-tile (39.4KB) into LDS async (queue absorbs latency, drained
// once per block), K-loop A becomes ds_read_b128. SD 608->616 so LDS rows are
// 2-way bank-aliased (free, m136) while keeping gload_lds's linear-dest rule
// (pad lives in the global S layout; accum writes stride 616).
// B stays direct from L2 (Wt 272KB). LDS caps 4 blocks/CU -> 16 waves/CU.

// ---------------- problem constants ----------------
#define NENT     100000
#define NREL     474
#define DIM      200
#define NBASES   100
#define NEDGES   500000
#define NTRIPLES 200000

#define CHUNK    50000     // nodes per S-buffer chunk
#define NCHUNKS  2
#define SD       616       // padded S row stride (bf16): 600 data + 8 zero + 8 unread
#define KD       608       // Wt row stride (bf16)
#define NPAD     224       // padded N (14 col-tiles of 16)
#define NTILW    7         // col-tiles per wave (4 waves: 2 row x 2 col groups)

// workspace byte offsets (1024-aligned regions)
#define OFF_R1    0UL           // 474*200*4 = 379200
#define OFF_R2    380928UL
#define OFF_R3    761856UL
#define OFF_R1B   1142784UL     // 474*200*2 = 189600 (bf16)
#define OFF_R2B   1335296UL
#define OFF_DEG   1527808UL     // 100000*4
#define OFF_CUR   1929216UL
#define OFF_CSR   2330624UL     // 100001*4
#define OFF_BSUM  2732032UL
#define OFF_BOFF  2736128UL
#define OFF_CSRC  2740224UL     // 500000*4
#define OFF_CRY   4743168UL     // 500000*4
#define OFF_WT1   6746112UL     // 224*608*2 = 272384
#define OFF_WT2   7020544UL
#define OFF_ENTB  7294976UL     // 100000*200*2 = 40,000,000
#define OFF_X1B   47296512UL    // 40,000,000 (bf16 layer-1 output)
#define OFF_SBUF  87298048UL    // 50000*616*2 = 61,600,000
#define OFF_X2    148898816UL   // 100000*200*4 = 80,000,000
// total = 228,898,816 bytes (~218.3 MiB; R8's 228.1 MB passed)

typedef __attribute__((ext_vector_type(8))) short bf16x8;
typedef __attribute__((ext_vector_type(4))) float f32x4;

__device__ inline unsigned short f2bf(float f) {          // RNE
    unsigned u = __float_as_uint(f);
    return (unsigned short)((u + 0x7FFFu + ((u >> 16) & 1u)) >> 16);
}
__device__ inline float bf2f(unsigned short s) {
    return __uint_as_float(((unsigned)s) << 16);
}

// ---------------- tiny GEMM: C[MxN] = A[MxK] @ B[KxN] (relation chain, fp32) ----
__global__ __launch_bounds__(256) void k_small_gemm(
    const float* __restrict__ A, const float* __restrict__ B,
    float* __restrict__ C, int M, int K, int N)
{
    int tid = blockIdx.x * blockDim.x + threadIdx.x;
    if (tid >= M * N) return;
    int row = tid / N, col = tid - row * N;
    const float* a = A + (long)row * K;
    float acc = 0.f;
    int k = 0;
    for (; k + 4 <= K; k += 4) {
        acc = fmaf(a[k + 0], B[(k + 0) * N + col], acc);
        acc = fmaf(a[k + 1], B[(k + 1) * N + col], acc);
        acc = fmaf(a[k + 2], B[(k + 2) * N + col], acc);
        acc = fmaf(a[k + 3], B[(k + 3) * N + col], acc);
    }
    for (; k < K; ++k) acc = fmaf(a[k], B[k * N + col], acc);
    C[tid] = acc;
}

// ---------------- fp32 -> bf16 table (relations) ----------------
__global__ __launch_bounds__(256) void k_rb(const float* __restrict__ in,
                                            unsigned short* __restrict__ out, int n)
{
    int i = blockIdx.x * 256 + threadIdx.x;
    if (i < n) out[i] = f2bf(in[i]);
}

// ---------------- W[600][200] fp32 -> Wt[224][608] bf16 (transposed, padded) ----
__global__ __launch_bounds__(256) void k_wt(const float* __restrict__ W,
                                            unsigned short* __restrict__ Wt)
{
    int i = blockIdx.x * 256 + threadIdx.x;
    if (i >= NPAD * KD) return;
    int c = i / KD, k = i - c * KD;
    float v = (c < 200 && k < 600) ? W[k * 200 + c] : 0.f;
    Wt[i] = f2bf(v);
}

// ---------------- ent[entids] fp32 -> bf16 table ----------------
__global__ __launch_bounds__(256) void k_entb(const float4* __restrict__ ent,
                                              const int* __restrict__ ids,
                                              ushort4* __restrict__ out)
{
    int i = blockIdx.x * 256 + threadIdx.x;     // over NENT*50
    if (i >= NENT * 50) return;
    int node = i / 50, j = i - node * 50;
    float4 v = ent[(long)ids[node] * 50 + j];
    ushort4 o;
    o.x = f2bf(v.x); o.y = f2bf(v.y); o.z = f2bf(v.z); o.w = f2bf(v.w);
    out[i] = o;
}

// ---------------- CSR build ----------------
__global__ __launch_bounds__(256) void k_hist(const int* __restrict__ ei, int* __restrict__ deg)
{
    int e = blockIdx.x * blockDim.x + threadIdx.x;
    if (e >= NEDGES) return;
    atomicAdd(&deg[ei[NEDGES + e]], 1);
}

__global__ __launch_bounds__(256) void k_scanA(
    const int* __restrict__ deg, int* __restrict__ out, int* __restrict__ bsum)
{
    __shared__ int sd[256];
    int t = threadIdx.x, b = blockIdx.x;
    int base = b * 1024 + t * 4;
    int v0 = (base + 0 < NENT) ? deg[base + 0] : 0;
    int v1 = (base + 1 < NENT) ? deg[base + 1] : 0;
    int v2 = (base + 2 < NENT) ? deg[base + 2] : 0;
    int v3 = (base + 3 < NENT) ? deg[base + 3] : 0;
    int s = v0 + v1 + v2 + v3;
    sd[t] = s; __syncthreads();
    for (int off = 1; off < 256; off <<= 1) {
        int x = (t >= off) ? sd[t - off] : 0;
        __syncthreads();
        sd[t] += x;
        __syncthreads();
    }
    int excl = sd[t] - s;
    if (base + 0 < NENT) out[base + 0] = excl;
    if (base + 1 < NENT) out[base + 1] = excl + v0;
    if (base + 2 < NENT) out[base + 2] = excl + v0 + v1;
    if (base + 3 < NENT) out[base + 3] = excl + v0 + v1 + v2;
    if (t == 255) bsum[b] = sd[255];
}

__global__ __launch_bounds__(128) void k_scanB(
    const int* __restrict__ bsum, int* __restrict__ boff, int nb)
{
    __shared__ int sd[128];
    int t = threadIdx.x;
    int s = (t < nb) ? bsum[t] : 0;
    sd[t] = s; __syncthreads();
    for (int off = 1; off < 128; off <<= 1) {
        int x = (t >= off) ? sd[t - off] : 0;
        __syncthreads();
        sd[t] += x;
        __syncthreads();
    }
    if (t < nb) boff[t] = sd[t] - s;
}

__global__ __launch_bounds__(256) void k_scanC(int* __restrict__ csr, const int* __restrict__ boff)
{
    int t = threadIdx.x, b = blockIdx.x;
    int base = b * 1024 + t * 4;
    int add = boff[b];
    #pragma unroll
    for (int i = 0; i < 4; ++i)
        if (base + i < NENT) csr[base + i] += add;
    if (b == 0 && t == 0) csr[NENT] = NEDGES;
}

__global__ __launch_bounds__(256) void k_scatter(
    const int* __restrict__ ei, const int* __restrict__ et, const int* __restrict__ y,
    const int* __restrict__ csr, int* __restrict__ cur,
    int* __restrict__ csrc, int* __restrict__ cry)
{
    int e = blockIdx.x * blockDim.x + threadIdx.x;
    if (e >= NEDGES) return;
    int dst = ei[NEDGES + e];
    int pos = csr[dst] + atomicAdd(&cur[dst], 1);
    csrc[pos] = ei[e];
    cry[pos]  = et[e] | (y[e] << 16);
}

// ---------------- per-node bucketed message accumulation (all-bf16 gather) ----------
// one wave per node; lanes 0..49 each own 4 dims of the 200-dim row
__global__ __launch_bounds__(256) void k_accum(
    const unsigned short* __restrict__ xb,   // [NENT][200] bf16
    const unsigned short* __restrict__ rb,   // [NREL][200] bf16
    const int* __restrict__ csr, const int* __restrict__ csrc, const int* __restrict__ cry,
    unsigned short* __restrict__ S, int nodeBase)
{
    int wv   = (blockIdx.x * blockDim.x + threadIdx.x) >> 6;   // 0..CHUNK-1
    int lane = threadIdx.x & 63;
    unsigned short* srow = S + (long)wv * SD;
    if (lane >= 50) {
        if (lane == 50 || lane == 51) {      // zero the K-pad (cols 600..615)
            uint4 z; z.x = z.y = z.z = z.w = 0u;
            *(uint4*)(srow + 600 + (lane - 50) * 8) = z;
        }
        return;
    }
    int v = nodeBase + wv;
    int start = csr[v], end = csr[v + 1];
    float4 a0 = {0,0,0,0}, a1 = {0,0,0,0}, a2 = {0,0,0,0};
    for (int e = start; e < end; ++e) {
        int src = csrc[e];
        int ry  = cry[e];
        int rel = ry & 0xFFFF;
        int k   = ry >> 16;
        ushort4 xv = *(const ushort4*)(xb + (long)src * 200 + lane * 4);
        ushort4 rv = *(const ushort4*)(rb + (long)rel * 200 + lane * 4);
        float mx = bf2f(xv.x) + bf2f(rv.x), my = bf2f(xv.y) + bf2f(rv.y);
        float mz = bf2f(xv.z) + bf2f(rv.z), mw = bf2f(xv.w) + bf2f(rv.w);
        if (k == 0)      { a0.x += mx; a0.y += my; a0.z += mz; a0.w += mw; }
        else if (k == 1) { a1.x += mx; a1.y += my; a1.z += mz; a1.w += mw; }
        else             { a2.x += mx; a2.y += my; a2.z += mz; a2.w += mw; }
    }
    ushort4 o;
    o.x = f2bf(a0.x); o.y = f2bf(a0.y); o.z = f2bf(a0.z); o.w = f2bf(a0.w);
    *(ushort4*)(srow +   0 + lane * 4) = o;
    o.x = f2bf(a1.x); o.y = f2bf(a1.y); o.z = f2bf(a1.z); o.w = f2bf(a1.w);
    *(ushort4*)(srow + 200 + lane * 4) = o;
    o.x = f2bf(a2.x); o.y = f2bf(a2.y); o.z = f2bf(a2.z); o.w = f2bf(a2.w);
    *(ushort4*)(srow + 400 + lane * 4) = o;
}

// ---------------- MFMA GEMM: X = tanh( S[M x 616]bf16 @ Wt^T[608 x 224]bf16 ) ------
// Block = 4 waves = 32 rows x 224 cols; wave = 16 rows x 7 col-tiles (acc 28 VGPR).
// S-tile async-staged to LDS (32x616 bf16 = 39,424B; 4 blocks/CU): global_load_lds
// width 16, wave-uniform LDS base + lane*16, per-lane global src (linear layout).
// ds_read_b128 A-frags: row stride 308 words == 20 mod 32 -> 2-way bank alias (free).
// B frag direct from L2-resident Wt.
template<int OUTBF>
__global__ __launch_bounds__(256) void k_gemm_mfma(
    const unsigned short* __restrict__ S, const unsigned short* __restrict__ Wt,
    void* __restrict__ Xout, int nrows, int rowBase)
{
    __shared__ unsigned short Asl[32 * SD];   // 39,424 B
    int tid  = threadIdx.x;
    int wid  = tid >> 6;                      // 0..3
    int lane = tid & 63;
    int row0 = blockIdx.x * 32;

    // ---- async stage S[row0 .. row0+32) -> LDS (77 x 16B chunks per row) ----
    int rowsLeft = nrows - row0;
    int vrows = rowsLeft < 32 ? rowsLeft : 32;
    int vch = vrows * (SD * 2 / 16);          // valid 16B chunks (<= 2464)
    const unsigned short* srcBase = S + (long)row0 * SD;
    #pragma unroll
    for (int i = 0; i < 10; ++i) {            // 10*256 = 2560 >= 2464
        int chunk = i * 256 + tid;
        if (chunk < vch) {
            __builtin_amdgcn_global_load_lds(
                (const __attribute__((address_space(1))) void*)(srcBase + chunk * 8),
                (__attribute__((address_space(3))) void*)(Asl + (i * 256 + wid * 64) * 8),
                16, 0, 0);
        }
    }
    __syncthreads();

    int l15 = lane & 15;
    int l4  = lane >> 4;
    int nt0 = (wid >> 1) * NTILW;             // 0 or 7
    const unsigned short* pw = Wt + (long)(nt0 * 16 + l15) * KD + l4 * 8;
    const unsigned short* pa = Asl + ((wid & 1) * 16 + l15) * SD + l4 * 8;

    f32x4 acc[NTILW] = {};
    for (int kt = 0; kt < 19; ++kt) {
        bf16x8 a = *(const bf16x8*)(pa + kt * 32);        // ds_read_b128
        #pragma unroll
        for (int nt = 0; nt < NTILW; ++nt) {
            bf16x8 b = *(const bf16x8*)(pw + nt * 16 * KD + kt * 32);
            acc[nt] = __builtin_amdgcn_mfma_f32_16x16x32_bf16(a, b, acc[nt], 0, 0, 0);
        }
    }

    int row0w = row0 + (wid & 1) * 16;
    #pragma unroll
    for (int nt = 0; nt < NTILW; ++nt) {
        int col = (nt0 + nt) * 16 + l15;
        bool cok = (col < DIM);
        #pragma unroll
        for (int i = 0; i < 4; ++i) {
            int r = row0w + l4 * 4 + i;
            if (cok && r < nrows) {
                float v = tanhf(acc[nt][i]);
                if (OUTBF) ((unsigned short*)Xout)[(long)(rowBase + r) * DIM + col] = f2bf(v);
                else       ((float*)Xout)[(long)(rowBase + r) * DIM + col] = v;
            }
        }
    }
}

// ---------------- row L2-normalize (in place, fp32) ----------------
__global__ __launch_bounds__(256) void k_norm(float4* __restrict__ x)
{
    int wv   = (blockIdx.x * blockDim.x + threadIdx.x) >> 6;
    int lane = threadIdx.x & 63;
    float4 v = {0,0,0,0};
    if (lane < 50) v = x[(long)wv * 50 + lane];
    float ss = v.x*v.x + v.y*v.y + v.z*v.z + v.w*v.w;
    for (int off = 1; off < 64; off <<= 1) ss += __shfl_xor(ss, off);
    float scale = 1.f / fmaxf(sqrtf(ss), 1e-12f);
    if (lane < 50) {
        v.x *= scale; v.y *= scale; v.z *= scale; v.w *= scale;
        x[(long)wv * 50 + lane] = v;
    }
}

// ---------------- triple scoring ----------------
__global__ __launch_bounds__(256) void k_score(
    const float4* __restrict__ x, const float4* __restrict__ r,
    const int* __restrict__ tri, float* __restrict__ out)
{
    int wv   = (blockIdx.x * blockDim.x + threadIdx.x) >> 6;
    int lane = threadIdx.x & 63;
    if (wv >= NTRIPLES) return;
    int h = tri[wv * 3 + 0], rel = tri[wv * 3 + 1], t = tri[wv * 3 + 2];
    float p = 0.f;
    if (lane < 50) {
        float4 hv = x[(long)h * 50 + lane];
        float4 rv = r[(long)rel * 50 + lane];
        float4 tv = x[(long)t * 50 + lane];
        p = fabsf(hv.x + rv.x - tv.x) + fabsf(hv.y + rv.y - tv.y)
          + fabsf(hv.z + rv.z - tv.z) + fabsf(hv.w + rv.w - tv.w);
    }
    for (int off = 1; off < 64; off <<= 1) p += __shfl_xor(p, off);
    if (lane == 0) out[wv] = 1.f / (1.f + expf(-p));
}

// ---------------- launch ----------------
extern "C" void kernel_launch(void* const* d_in, const int* in_sizes, int n_in,
                              void* d_out, int out_size, void* d_ws, size_t ws_size,
                              hipStream_t stream)
{
    const float* ent    = (const float*)d_in[0];
    const float* bases  = (const float*)d_in[1];
    const float* coeff  = (const float*)d_in[2];
    const float* w1     = (const float*)d_in[3];
    const float* rw1    = (const float*)d_in[4];
    const float* w2     = (const float*)d_in[5];
    const float* rw2    = (const float*)d_in[6];
    const int*   entids = (const int*)d_in[7];
    const int*   ei     = (const int*)d_in[8];
    const int*   etype  = (const int*)d_in[9];
    const int*   yv     = (const int*)d_in[10];
    const int*   tri    = (const int*)d_in[11];
    float* out = (float*)d_out;

    char* ws = (char*)d_ws;
    float* r1   = (float*)(ws + OFF_R1);
    float* r2   = (float*)(ws + OFF_R2);
    float* r3   = (float*)(ws + OFF_R3);
    unsigned short* r1b = (unsigned short*)(ws + OFF_R1B);
    unsigned short* r2b = (unsigned short*)(ws + OFF_R2B);
    int* deg    = (int*)(ws + OFF_DEG);
    int* cur    = (int*)(ws + OFF_CUR);
    int* csr    = (int*)(ws + OFF_CSR);
    int* bsum   = (int*)(ws + OFF_BSUM);
    int* boff   = (int*)(ws + OFF_BOFF);
    int* csrc   = (int*)(ws + OFF_CSRC);
    int* cry    = (int*)(ws + OFF_CRY);
    unsigned short* wt1  = (unsigned short*)(ws + OFF_WT1);
    unsigned short* wt2  = (unsigned short*)(ws + OFF_WT2);
    unsigned short* entb = (unsigned short*)(ws + OFF_ENTB);
    unsigned short* x1b  = (unsigned short*)(ws + OFF_X1B);
    unsigned short* Sbuf = (unsigned short*)(ws + OFF_SBUF);
    float* x2   = (float*)(ws + OFF_X2);

    hipMemsetAsync(ws + OFF_DEG, 0, OFF_CSR - OFF_DEG, stream);

    // relation chain (fp32): r1 = coeff@bases ; r2 = r1@rw1 ; r3 = r2@rw2
    {
        int tot = NREL * DIM;
        int nb = (tot + 255) / 256;
        k_small_gemm<<<nb, 256, 0, stream>>>(coeff, bases, r1, NREL, NBASES, DIM);
        k_small_gemm<<<nb, 256, 0, stream>>>(r1, rw1, r2, NREL, DIM, DIM);
        k_small_gemm<<<nb, 256, 0, stream>>>(r2, rw2, r3, NREL, DIM, DIM);
        k_rb<<<nb, 256, 0, stream>>>(r1, r1b, tot);
        k_rb<<<nb, 256, 0, stream>>>(r2, r2b, tot);
    }

    // weight transpose->bf16 (padded to 224 rows), entity table->bf16
    k_wt<<<(NPAD * KD + 255) / 256, 256, 0, stream>>>(w1, wt1);
    k_wt<<<(NPAD * KD + 255) / 256, 256, 0, stream>>>(w2, wt2);
    k_entb<<<(NENT * 50 + 255) / 256, 256, 0, stream>>>(
        (const float4*)ent, entids, (ushort4*)entb);

    // CSR by destination (shared by both layers)
    k_hist<<<(NEDGES + 255) / 256, 256, 0, stream>>>(ei, deg);
    int nScanBlocks = (NENT + 1023) / 1024;   // 98
    k_scanA<<<nScanBlocks, 256, 0, stream>>>(deg, csr, bsum);
    k_scanB<<<1, 128, 0, stream>>>(bsum, boff, nScanBlocks);
    k_scanC<<<nScanBlocks, 256, 0, stream>>>(csr, boff);
    k_scatter<<<(NEDGES + 255) / 256, 256, 0, stream>>>(ei, etype, yv, csr, cur, csrc, cry);

    int gblocks = (CHUNK + 31) / 32;     // 1563 blocks (4 waves: 2 row x 2 col groups)

    // layer 1: x1b = bf16(tanh(bucketed-segsum(entb[src]+r1[et]) @ w1))
    for (int c = 0; c < NCHUNKS; ++c) {
        int base = c * CHUNK;
        k_accum<<<CHUNK * 64 / 256, 256, 0, stream>>>(entb, r1b,
                                                      csr, csrc, cry, Sbuf, base);
        k_gemm_mfma<1><<<gblocks, 256, 0, stream>>>(Sbuf, wt1, (void*)x1b, CHUNK, base);
    }
    // layer 2: x2 = tanh(bucketed-segsum(x1b[src]+r2[et]) @ w2)   (fp32 out)
    for (int c = 0; c < NCHUNKS; ++c) {
        int base = c * CHUNK;
        k_accum<<<CHUNK * 64 / 256, 256, 0, stream>>>(x1b, r2b,
                                                      csr, csrc, cry, Sbuf, base);
        k_gemm_mfma<0><<<gblocks, 256, 0, stream>>>(Sbuf, wt2, (void*)x2, CHUNK, base);
    }

    k_norm<<<NENT / 4, 256, 0, stream>>>((float4*)x2);
    k_score<<<(NTRIPLES + 3) / 4, 256, 0, stream>>>(
        (const float4*)x2, (const float4*)r3, tri, out);
}

// Round 12
// 743.258 us; speedup vs baseline: 2.2860x; 1.0641x over previous
//
#include <hip/hip_runtime.h>
#include <math.h>

// R12 = R11 resubmitted verbatim (R11 bench failed: GPU acquisition timeout; never measured).
// R11: GEMM restructured around the R10 falsification.
// R10 evidence: LDS-staging A was NEUTRAL (77.3->76.9us, MfmaUtil 6.5->6.7%) =>
// A-path was never the bottleneck. VGPR=52 shows compiler allocates NO B-prefetch
// registers: each kt waits a full L2 latency on 7 B-loads with ~35cy of MFMA.
// Fix: (1) drop LDS staging (it only capped residency at 4 blocks/CU);
// (2) waves share the block's 32 rows, each owns 4 col-tiles of N padded to 256
//     (B-frag reused by 2 row-frags -> 8 MFMA per 4 B-loads);
// (3) explicit depth-1 register prefetch of next-kt A+B, full kt unroll,
//     __launch_bounds__(256,4) pinning VGPR<=128 (~100 est).

// ---------------- problem constants ----------------
#define NENT     100000
#define NREL     474
#define DIM      200
#define NBASES   100
#define NEDGES   500000
#define NTRIPLES 200000

#define CHUNK    50000     // nodes per S-buffer chunk
#define NCHUNKS  2
#define SD       608       // S row stride (bf16): 600 data + 8 zero pad
#define KD       608       // Wt row stride (bf16)
#define NPAD     256       // padded N (16 col-tiles of 16; 4 tiles per wave)

// workspace byte offsets (1024-aligned regions)
#define OFF_R1    0UL           // 474*200*4 = 379200
#define OFF_R2    380928UL
#define OFF_R3    761856UL
#define OFF_R1B   1142784UL     // 474*200*2 = 189600 (bf16)
#define OFF_R2B   1335296UL
#define OFF_DEG   1527808UL     // 100000*4
#define OFF_CUR   1929216UL
#define OFF_CSR   2330624UL     // 100001*4
#define OFF_BSUM  2732032UL
#define OFF_BOFF  2736128UL
#define OFF_CSRC  2740224UL     // 500000*4
#define OFF_CRY   4743168UL     // 500000*4
#define OFF_WT1   6746112UL     // 256*608*2 = 311296
#define OFF_WT2   7057408UL
#define OFF_ENTB  7368704UL     // 100000*200*2 = 40,000,000
#define OFF_X1B   47369216UL    // 40,000,000 (bf16 layer-1 output)
#define OFF_SBUF  87369728UL    // 50000*608*2 = 60,800,000
#define OFF_X2    148169728UL   // 100000*200*4 = 80,000,000
// total = 228,169,728 bytes (~217.6 MiB; R10's 228.9 MB passed)

typedef __attribute__((ext_vector_type(8))) short bf16x8;
typedef __attribute__((ext_vector_type(4))) float f32x4;

__device__ inline unsigned short f2bf(float f) {          // RNE
    unsigned u = __float_as_uint(f);
    return (unsigned short)((u + 0x7FFFu + ((u >> 16) & 1u)) >> 16);
}
__device__ inline float bf2f(unsigned short s) {
    return __uint_as_float(((unsigned)s) << 16);
}

// ---------------- tiny GEMM: C[MxN] = A[MxK] @ B[KxN] (relation chain, fp32) ----
__global__ __launch_bounds__(256) void k_small_gemm(
    const float* __restrict__ A, const float* __restrict__ B,
    float* __restrict__ C, int M, int K, int N)
{
    int tid = blockIdx.x * blockDim.x + threadIdx.x;
    if (tid >= M * N) return;
    int row = tid / N, col = tid - row * N;
    const float* a = A + (long)row * K;
    float acc = 0.f;
    int k = 0;
    for (; k + 4 <= K; k += 4) {
        acc = fmaf(a[k + 0], B[(k + 0) * N + col], acc);
        acc = fmaf(a[k + 1], B[(k + 1) * N + col], acc);
        acc = fmaf(a[k + 2], B[(k + 2) * N + col], acc);
        acc = fmaf(a[k + 3], B[(k + 3) * N + col], acc);
    }
    for (; k < K; ++k) acc = fmaf(a[k], B[k * N + col], acc);
    C[tid] = acc;
}

// ---------------- fp32 -> bf16 table (relations) ----------------
__global__ __launch_bounds__(256) void k_rb(const float* __restrict__ in,
                                            unsigned short* __restrict__ out, int n)
{
    int i = blockIdx.x * 256 + threadIdx.x;
    if (i < n) out[i] = f2bf(in[i]);
}

// ---------------- W[600][200] fp32 -> Wt[256][608] bf16 (transposed, padded) ----
__global__ __launch_bounds__(256) void k_wt(const float* __restrict__ W,
                                            unsigned short* __restrict__ Wt)
{
    int i = blockIdx.x * 256 + threadIdx.x;
    if (i >= NPAD * KD) return;
    int c = i / KD, k = i - c * KD;
    float v = (c < 200 && k < 600) ? W[k * 200 + c] : 0.f;
    Wt[i] = f2bf(v);
}

// ---------------- ent[entids] fp32 -> bf16 table ----------------
__global__ __launch_bounds__(256) void k_entb(const float4* __restrict__ ent,
                                              const int* __restrict__ ids,
                                              ushort4* __restrict__ out)
{
    int i = blockIdx.x * 256 + threadIdx.x;     // over NENT*50
    if (i >= NENT * 50) return;
    int node = i / 50, j = i - node * 50;
    float4 v = ent[(long)ids[node] * 50 + j];
    ushort4 o;
    o.x = f2bf(v.x); o.y = f2bf(v.y); o.z = f2bf(v.z); o.w = f2bf(v.w);
    out[i] = o;
}

// ---------------- CSR build ----------------
__global__ __launch_bounds__(256) void k_hist(const int* __restrict__ ei, int* __restrict__ deg)
{
    int e = blockIdx.x * blockDim.x + threadIdx.x;
    if (e >= NEDGES) return;
    atomicAdd(&deg[ei[NEDGES + e]], 1);
}

__global__ __launch_bounds__(256) void k_scanA(
    const int* __restrict__ deg, int* __restrict__ out, int* __restrict__ bsum)
{
    __shared__ int sd[256];
    int t = threadIdx.x, b = blockIdx.x;
    int base = b * 1024 + t * 4;
    int v0 = (base + 0 < NENT) ? deg[base + 0] : 0;
    int v1 = (base + 1 < NENT) ? deg[base + 1] : 0;
    int v2 = (base + 2 < NENT) ? deg[base + 2] : 0;
    int v3 = (base + 3 < NENT) ? deg[base + 3] : 0;
    int s = v0 + v1 + v2 + v3;
    sd[t] = s; __syncthreads();
    for (int off = 1; off < 256; off <<= 1) {
        int x = (t >= off) ? sd[t - off] : 0;
        __syncthreads();
        sd[t] += x;
        __syncthreads();
    }
    int excl = sd[t] - s;
    if (base + 0 < NENT) out[base + 0] = excl;
    if (base + 1 < NENT) out[base + 1] = excl + v0;
    if (base + 2 < NENT) out[base + 2] = excl + v0 + v1;
    if (base + 3 < NENT) out[base + 3] = excl + v0 + v1 + v2;
    if (t == 255) bsum[b] = sd[255];
}

__global__ __launch_bounds__(128) void k_scanB(
    const int* __restrict__ bsum, int* __restrict__ boff, int nb)
{
    __shared__ int sd[128];
    int t = threadIdx.x;
    int s = (t < nb) ? bsum[t] : 0;
    sd[t] = s; __syncthreads();
    for (int off = 1; off < 128; off <<= 1) {
        int x = (t >= off) ? sd[t - off] : 0;
        __syncthreads();
        sd[t] += x;
        __syncthreads();
    }
    if (t < nb) boff[t] = sd[t] - s;
}

__global__ __launch_bounds__(256) void k_scanC(int* __restrict__ csr, const int* __restrict__ boff)
{
    int t = threadIdx.x, b = blockIdx.x;
    int base = b * 1024 + t * 4;
    int add = boff[b];
    #pragma unroll
    for (int i = 0; i < 4; ++i)
        if (base + i < NENT) csr[base + i] += add;
    if (b == 0 && t == 0) csr[NENT] = NEDGES;
}

__global__ __launch_bounds__(256) void k_scatter(
    const int* __restrict__ ei, const int* __restrict__ et, const int* __restrict__ y,
    const int* __restrict__ csr, int* __restrict__ cur,
    int* __restrict__ csrc, int* __restrict__ cry)
{
    int e = blockIdx.x * blockDim.x + threadIdx.x;
    if (e >= NEDGES) return;
    int dst = ei[NEDGES + e];
    int pos = csr[dst] + atomicAdd(&cur[dst], 1);
    csrc[pos] = ei[e];
    cry[pos]  = et[e] | (y[e] << 16);
}

// ---------------- per-node bucketed message accumulation (all-bf16 gather) ----------
// one wave per node; lanes 0..49 each own 4 dims of the 200-dim row
__global__ __launch_bounds__(256) void k_accum(
    const unsigned short* __restrict__ xb,   // [NENT][200] bf16
    const unsigned short* __restrict__ rb,   // [NREL][200] bf16
    const int* __restrict__ csr, const int* __restrict__ csrc, const int* __restrict__ cry,
    unsigned short* __restrict__ S, int nodeBase)
{
    int wv   = (blockIdx.x * blockDim.x + threadIdx.x) >> 6;   // 0..CHUNK-1
    int lane = threadIdx.x & 63;
    unsigned short* srow = S + (long)wv * SD;
    if (lane >= 50) {
        if (lane == 50) {                    // zero the K-pad (cols 600..607)
            uint4 z; z.x = z.y = z.z = z.w = 0u;
            *(uint4*)(srow + 600) = z;
        }
        return;
    }
    int v = nodeBase + wv;
    int start = csr[v], end = csr[v + 1];
    float4 a0 = {0,0,0,0}, a1 = {0,0,0,0}, a2 = {0,0,0,0};
    for (int e = start; e < end; ++e) {
        int src = csrc[e];
        int ry  = cry[e];
        int rel = ry & 0xFFFF;
        int k   = ry >> 16;
        ushort4 xv = *(const ushort4*)(xb + (long)src * 200 + lane * 4);
        ushort4 rv = *(const ushort4*)(rb + (long)rel * 200 + lane * 4);
        float mx = bf2f(xv.x) + bf2f(rv.x), my = bf2f(xv.y) + bf2f(rv.y);
        float mz = bf2f(xv.z) + bf2f(rv.z), mw = bf2f(xv.w) + bf2f(rv.w);
        if (k == 0)      { a0.x += mx; a0.y += my; a0.z += mz; a0.w += mw; }
        else if (k == 1) { a1.x += mx; a1.y += my; a1.z += mz; a1.w += mw; }
        else             { a2.x += mx; a2.y += my; a2.z += mz; a2.w += mw; }
    }
    ushort4 o;
    o.x = f2bf(a0.x); o.y = f2bf(a0.y); o.z = f2bf(a0.z); o.w = f2bf(a0.w);
    *(ushort4*)(srow +   0 + lane * 4) = o;
    o.x = f2bf(a1.x); o.y = f2bf(a1.y); o.z = f2bf(a1.z); o.w = f2bf(a1.w);
    *(ushort4*)(srow + 200 + lane * 4) = o;
    o.x = f2bf(a2.x); o.y = f2bf(a2.y); o.z = f2bf(a2.z); o.w = f2bf(a2.w);
    *(ushort4*)(srow + 400 + lane * 4) = o;
}

// ---------------- MFMA GEMM: X = tanh( S[M x 608]bf16 @ Wt^T[608 x 256]bf16 ) ------
// Block = 4 waves, all sharing rows [row0, row0+32); wave wid owns col-tiles
// wid*4 .. wid*4+3 (N padded 256). Per kt: 2 A-frags + 4 B-frags (each B reused by
// both row-frags -> 8 MFMAs), next-kt A/B prefetched into named registers.
// acc = 2x4x4 = 32 VGPR; launch_bounds(256,4) pins >=4 waves/SIMD (VGPR<=128).
template<int OUTBF>
__global__ __launch_bounds__(256, 4) void k_gemm_mfma(
    const unsigned short* __restrict__ S, const unsigned short* __restrict__ Wt,
    void* __restrict__ Xout, int nrows, int rowBase)
{
    int wid  = threadIdx.x >> 6;          // 0..3 -> col-tile group
    int lane = threadIdx.x & 63;
    int l15  = lane & 15;
    int l4   = lane >> 4;
    int row0 = blockIdx.x * 32;
    int ra = row0 + l15;      if (ra >= nrows) ra = nrows - 1;   // clamp reads only
    int rb = row0 + 16 + l15; if (rb >= nrows) rb = nrows - 1;
    const unsigned short* pa0 = S  + (long)ra * SD + l4 * 8;
    const unsigned short* pa1 = S  + (long)rb * SD + l4 * 8;
    const unsigned short* pw  = Wt + (long)(wid * 64 + l15) * KD + l4 * 8;

    // depth-1 software pipeline: current regs + prefetch regs
    bf16x8 a0c = *(const bf16x8*)(pa0);
    bf16x8 a1c = *(const bf16x8*)(pa1);
    bf16x8 bc0 = *(const bf16x8*)(pw + 0 * 16 * KD);
    bf16x8 bc1 = *(const bf16x8*)(pw + 1 * 16 * KD);
    bf16x8 bc2 = *(const bf16x8*)(pw + 2 * 16 * KD);
    bf16x8 bc3 = *(const bf16x8*)(pw + 3 * 16 * KD);

    f32x4 acc0[4] = {};
    f32x4 acc1[4] = {};
    #pragma unroll
    for (int kt = 0; kt < 19; ++kt) {
        bf16x8 a0n, a1n, bn0, bn1, bn2, bn3;
        if (kt < 18) {
            int o = (kt + 1) * 32;
            a0n = *(const bf16x8*)(pa0 + o);
            a1n = *(const bf16x8*)(pa1 + o);
            bn0 = *(const bf16x8*)(pw + 0 * 16 * KD + o);
            bn1 = *(const bf16x8*)(pw + 1 * 16 * KD + o);
            bn2 = *(const bf16x8*)(pw + 2 * 16 * KD + o);
            bn3 = *(const bf16x8*)(pw + 3 * 16 * KD + o);
        }
        acc0[0] = __builtin_amdgcn_mfma_f32_16x16x32_bf16(a0c, bc0, acc0[0], 0, 0, 0);
        acc1[0] = __builtin_amdgcn_mfma_f32_16x16x32_bf16(a1c, bc0, acc1[0], 0, 0, 0);
        acc0[1] = __builtin_amdgcn_mfma_f32_16x16x32_bf16(a0c, bc1, acc0[1], 0, 0, 0);
        acc1[1] = __builtin_amdgcn_mfma_f32_16x16x32_bf16(a1c, bc1, acc1[1], 0, 0, 0);
        acc0[2] = __builtin_amdgcn_mfma_f32_16x16x32_bf16(a0c, bc2, acc0[2], 0, 0, 0);
        acc1[2] = __builtin_amdgcn_mfma_f32_16x16x32_bf16(a1c, bc2, acc1[2], 0, 0, 0);
        acc0[3] = __builtin_amdgcn_mfma_f32_16x16x32_bf16(a0c, bc3, acc0[3], 0, 0, 0);
        acc1[3] = __builtin_amdgcn_mfma_f32_16x16x32_bf16(a1c, bc3, acc1[3], 0, 0, 0);
        if (kt < 18) {
            a0c = a0n; a1c = a1n;
            bc0 = bn0; bc1 = bn1; bc2 = bn2; bc3 = bn3;
        }
    }

    #pragma unroll
    for (int nt = 0; nt < 4; ++nt) {
        int col = (wid * 4 + nt) * 16 + l15;
        bool cok = (col < DIM);
        #pragma unroll
        for (int i = 0; i < 4; ++i) {
            int r0 = row0 + l4 * 4 + i;
            if (cok && r0 < nrows) {
                float v = tanhf(acc0[nt][i]);
                if (OUTBF) ((unsigned short*)Xout)[(long)(rowBase + r0) * DIM + col] = f2bf(v);
                else       ((float*)Xout)[(long)(rowBase + r0) * DIM + col] = v;
            }
            int r1 = r0 + 16;
            if (cok && r1 < nrows) {
                float v = tanhf(acc1[nt][i]);
                if (OUTBF) ((unsigned short*)Xout)[(long)(rowBase + r1) * DIM + col] = f2bf(v);
                else       ((float*)Xout)[(long)(rowBase + r1) * DIM + col] = v;
            }
        }
    }
}

// ---------------- row L2-normalize (in place, fp32) ----------------
__global__ __launch_bounds__(256) void k_norm(float4* __restrict__ x)
{
    int wv   = (blockIdx.x * blockDim.x + threadIdx.x) >> 6;
    int lane = threadIdx.x & 63;
    float4 v = {0,0,0,0};
    if (lane < 50) v = x[(long)wv * 50 + lane];
    float ss = v.x*v.x + v.y*v.y + v.z*v.z + v.w*v.w;
    for (int off = 1; off < 64; off <<= 1) ss += __shfl_xor(ss, off);
    float scale = 1.f / fmaxf(sqrtf(ss), 1e-12f);
    if (lane < 50) {
        v.x *= scale; v.y *= scale; v.z *= scale; v.w *= scale;
        x[(long)wv * 50 + lane] = v;
    }
}

// ---------------- triple scoring ----------------
__global__ __launch_bounds__(256) void k_score(
    const float4* __restrict__ x, const float4* __restrict__ r,
    const int* __restrict__ tri, float* __restrict__ out)
{
    int wv   = (blockIdx.x * blockDim.x + threadIdx.x) >> 6;
    int lane = threadIdx.x & 63;
    if (wv >= NTRIPLES) return;
    int h = tri[wv * 3 + 0], rel = tri[wv * 3 + 1], t = tri[wv * 3 + 2];
    float p = 0.f;
    if (lane < 50) {
        float4 hv = x[(long)h * 50 + lane];
        float4 rv = r[(long)rel * 50 + lane];
        float4 tv = x[(long)t * 50 + lane];
        p = fabsf(hv.x + rv.x - tv.x) + fabsf(hv.y + rv.y - tv.y)
          + fabsf(hv.z + rv.z - tv.z) + fabsf(hv.w + rv.w - tv.w);
    }
    for (int off = 1; off < 64; off <<= 1) p += __shfl_xor(p, off);
    if (lane == 0) out[wv] = 1.f / (1.f + expf(-p));
}

// ---------------- launch ----------------
extern "C" void kernel_launch(void* const* d_in, const int* in_sizes, int n_in,
                              void* d_out, int out_size, void* d_ws, size_t ws_size,
                              hipStream_t stream)
{
    const float* ent    = (const float*)d_in[0];
    const float* bases  = (const float*)d_in[1];
    const float* coeff  = (const float*)d_in[2];
    const float* w1     = (const float*)d_in[3];
    const float* rw1    = (const float*)d_in[4];
    const float* w2     = (const float*)d_in[5];
    const float* rw2    = (const float*)d_in[6];
    const int*   entids = (const int*)d_in[7];
    const int*   ei     = (const int*)d_in[8];
    const int*   etype  = (const int*)d_in[9];
    const int*   yv     = (const int*)d_in[10];
    const int*   tri    = (const int*)d_in[11];
    float* out = (float*)d_out;

    char* ws = (char*)d_ws;
    float* r1   = (float*)(ws + OFF_R1);
    float* r2   = (float*)(ws + OFF_R2);
    float* r3   = (float*)(ws + OFF_R3);
    unsigned short* r1b = (unsigned short*)(ws + OFF_R1B);
    unsigned short* r2b = (unsigned short*)(ws + OFF_R2B);
    int* deg    = (int*)(ws + OFF_DEG);
    int* cur    = (int*)(ws + OFF_CUR);
    int* csr    = (int*)(ws + OFF_CSR);
    int* bsum   = (int*)(ws + OFF_BSUM);
    int* boff   = (int*)(ws + OFF_BOFF);
    int* csrc   = (int*)(ws + OFF_CSRC);
    int* cry    = (int*)(ws + OFF_CRY);
    unsigned short* wt1  = (unsigned short*)(ws + OFF_WT1);
    unsigned short* wt2  = (unsigned short*)(ws + OFF_WT2);
    unsigned short* entb = (unsigned short*)(ws + OFF_ENTB);
    unsigned short* x1b  = (unsigned short*)(ws + OFF_X1B);
    unsigned short* Sbuf = (unsigned short*)(ws + OFF_SBUF);
    float* x2   = (float*)(ws + OFF_X2);

    hipMemsetAsync(ws + OFF_DEG, 0, OFF_CSR - OFF_DEG, stream);

    // relation chain (fp32): r1 = coeff@bases ; r2 = r1@rw1 ; r3 = r2@rw2
    {
        int tot = NREL * DIM;
        int nb = (tot + 255) / 256;
        k_small_gemm<<<nb, 256, 0, stream>>>(coeff, bases, r1, NREL, NBASES, DIM);
        k_small_gemm<<<nb, 256, 0, stream>>>(r1, rw1, r2, NREL, DIM, DIM);
        k_small_gemm<<<nb, 256, 0, stream>>>(r2, rw2, r3, NREL, DIM, DIM);
        k_rb<<<nb, 256, 0, stream>>>(r1, r1b, tot);
        k_rb<<<nb, 256, 0, stream>>>(r2, r2b, tot);
    }

    // weight transpose->bf16 (padded to 256 rows), entity table->bf16
    k_wt<<<(NPAD * KD + 255) / 256, 256, 0, stream>>>(w1, wt1);
    k_wt<<<(NPAD * KD + 255) / 256, 256, 0, stream>>>(w2, wt2);
    k_entb<<<(NENT * 50 + 255) / 256, 256, 0, stream>>>(
        (const float4*)ent, entids, (ushort4*)entb);

    // CSR by destination (shared by both layers)
    k_hist<<<(NEDGES + 255) / 256, 256, 0, stream>>>(ei, deg);
    int nScanBlocks = (NENT + 1023) / 1024;   // 98
    k_scanA<<<nScanBlocks, 256, 0, stream>>>(deg, csr, bsum);
    k_scanB<<<1, 128, 0, stream>>>(bsum, boff, nScanBlocks);
    k_scanC<<<nScanBlocks, 256, 0, stream>>>(csr, boff);
    k_scatter<<<(NEDGES + 255) / 256, 256, 0, stream>>>(ei, etype, yv, csr, cur, csrc, cry);

    int gblocks = (CHUNK + 31) / 32;     // 1563 blocks

    // layer 1: x1b = bf16(tanh(bucketed-segsum(entb[src]+r1[et]) @ w1))
    for (int c = 0; c < NCHUNKS; ++c) {
        int base = c * CHUNK;
        k_accum<<<CHUNK * 64 / 256, 256, 0, stream>>>(entb, r1b,
                                                      csr, csrc, cry, Sbuf, base);
        k_gemm_mfma<1><<<gblocks, 256, 0, stream>>>(Sbuf, wt1, (void*)x1b, CHUNK, base);
    }
    // layer 2: x2 = tanh(bucketed-segsum(x1b[src]+r2[et]) @ w2)   (fp32 out)
    for (int c = 0; c < NCHUNKS; ++c) {
        int base = c * CHUNK;
        k_accum<<<CHUNK * 64 / 256, 256, 0, stream>>>(x1b, r2b,
                                                      csr, csrc, cry, Sbuf, base);
        k_gemm_mfma<0><<<gblocks, 256, 0, stream>>>(Sbuf, wt2, (void*)x2, CHUNK, base);
    }

    k_norm<<<NENT / 4, 256, 0, stream>>>((float4*)x2);
    k_score<<<(NTRIPLES + 3) / 4, 256, 0, stream>>>(
        (const float4*)x2, (const float4*)r3, tri, out);
}